// Round 1
// baseline (4088.242 us; speedup 1.0000x reference)
//
#include <hip/hip_runtime.h>
#include <hip/hip_bf16.h>
#include <math.h>

// Problem constants (from reference)
constexpr int NN    = 30000;   // nodes
constexpr int DIM   = 128;     // feature dim
constexpr int KH    = 3;       // history steps
constexpr int NC    = 6;       // conv stack depth
constexpr int EE    = 480000;  // edges

// ---------------------------------------------------------------------------
// Generic fp32 GEMM: C[M,Nc] (+)= A[M,Kc] @ B  (+ bias) (ReLU)
// B non-transposed: B[k*ldb + n] ; B transposed (BT): B[n*ldb + k]
// Block: 256 threads, 64x64 output tile, K-tile 16, 4x4 per thread.
// ---------------------------------------------------------------------------
template<bool BT, bool ACC, bool BIAS, bool RELU>
__global__ __launch_bounds__(256) void gemm_kernel(
    const float* __restrict__ A, int lda,
    const float* __restrict__ B, int ldb,
    const float* __restrict__ bias,
    float* __restrict__ C, int ldc,
    int M, int Nc, int Kc)
{
    __shared__ __align__(16) float As[16][68];  // [kk][m]
    __shared__ __align__(16) float Bs[16][68];  // [kk][n]
    const int tid = threadIdx.x;
    const int tx  = tid & 15;   // n
    const int ty  = tid >> 4;   // m
    const int bm  = blockIdx.y * 64;
    const int bn  = blockIdx.x * 64;

    float acc[4][4] = {};

    const int a_m = tid >> 2;        // 0..63
    const int a_k = (tid & 3) * 4;   // 0,4,8,12

    for (int k0 = 0; k0 < Kc; k0 += 16) {
        // ---- stage A tile (64m x 16k) ----
        {
            int m = bm + a_m;
            float4 v = make_float4(0.f, 0.f, 0.f, 0.f);
            if (m < M) v = *(const float4*)(A + (size_t)m * lda + k0 + a_k);
            As[a_k + 0][a_m] = v.x; As[a_k + 1][a_m] = v.y;
            As[a_k + 2][a_m] = v.z; As[a_k + 3][a_m] = v.w;
        }
        // ---- stage B tile (16k x 64n) ----
        if (!BT) {
            int kk = tid >> 4;            // 0..15
            int nq = (tid & 15) * 4;      // 0..60
            float4 v = *(const float4*)(B + (size_t)(k0 + kk) * ldb + bn + nq);
            *(float4*)&Bs[kk][nq] = v;
        } else {
            int nl = tid >> 2;            // 0..63
            int kq = (tid & 3) * 4;
            float4 v = *(const float4*)(B + (size_t)(bn + nl) * ldb + k0 + kq);
            Bs[kq + 0][nl] = v.x; Bs[kq + 1][nl] = v.y;
            Bs[kq + 2][nl] = v.z; Bs[kq + 3][nl] = v.w;
        }
        __syncthreads();
        #pragma unroll
        for (int kk = 0; kk < 16; ++kk) {
            float4 av = *(const float4*)&As[kk][ty * 4];
            float4 bv = *(const float4*)&Bs[kk][tx * 4];
            float a[4] = {av.x, av.y, av.z, av.w};
            float b[4] = {bv.x, bv.y, bv.z, bv.w};
            #pragma unroll
            for (int i = 0; i < 4; ++i)
                #pragma unroll
                for (int j = 0; j < 4; ++j)
                    acc[i][j] += a[i] * b[j];
        }
        __syncthreads();
    }

    #pragma unroll
    for (int i = 0; i < 4; ++i) {
        int m = bm + ty * 4 + i;
        if (m >= M) continue;
        #pragma unroll
        for (int j = 0; j < 4; ++j) {
            int n = bn + tx * 4 + j;
            float v = acc[i][j];
            if (BIAS) v += bias[n];
            if (ACC)  v += C[(size_t)m * ldc + n];
            if (RELU) v = fmaxf(v, 0.f);
            C[(size_t)m * ldc + n] = v;
        }
    }
}

static inline void gemm(hipStream_t s, bool BT, bool ACC, bool BIAS_, bool RELU_,
                        const float* A, int lda, const float* B, int ldb,
                        const float* bias, float* C, int ldc,
                        int M, int Nc, int Kc)
{
    dim3 grid(Nc / 64, (M + 63) / 64);
    dim3 blk(256);
#define GO(bt, ac, bi, re) gemm_kernel<bt, ac, bi, re><<<grid, blk, 0, s>>>(A, lda, B, ldb, bias, C, ldc, M, Nc, Kc)
    if (!BT) {
        if (!ACC) {
            if (BIAS_) { if (RELU_) GO(false, false, true, true); else GO(false, false, true, false); }
            else       { GO(false, false, false, false); }
        } else {
            if (RELU_) GO(false, true, false, true);
            else       GO(false, true, false, false);
        }
    } else {
        if (!ACC) GO(true, false, true, false);
        else      GO(true, true, true, false);
    }
#undef GO
}

// ---------------------------------------------------------------------------
// CSR build: histogram -> exclusive scan -> fill (int atomics only)
// ---------------------------------------------------------------------------
__global__ void hist_kernel(const int* __restrict__ dst, int* __restrict__ cnt, int e)
{
    int i = blockIdx.x * 256 + threadIdx.x;
    if (i < e) atomicAdd(&cnt[dst[i]], 1);
}

__global__ __launch_bounds__(1024) void scan_kernel(const int* __restrict__ cnt,
                                                    int* __restrict__ off, int n)
{
    __shared__ int buf[1024];
    __shared__ int s_carry;
    if (threadIdx.x == 0) s_carry = 0;
    __syncthreads();
    for (int base = 0; base < n; base += 1024) {
        int i = base + threadIdx.x;
        int v = (i < n) ? cnt[i] : 0;
        buf[threadIdx.x] = v;
        __syncthreads();
        #pragma unroll
        for (int ofs = 1; ofs < 1024; ofs <<= 1) {
            int t = (threadIdx.x >= ofs) ? buf[threadIdx.x - ofs] : 0;
            __syncthreads();
            buf[threadIdx.x] += t;
            __syncthreads();
        }
        int carry = s_carry;
        if (i < n) off[i] = carry + buf[threadIdx.x] - v;  // exclusive
        __syncthreads();
        if (threadIdx.x == 0) s_carry = carry + buf[1023];
        __syncthreads();
    }
    if (threadIdx.x == 0) off[n] = s_carry;
}

__global__ void fill_kernel(const int* __restrict__ src, const int* __restrict__ dst,
                            int* __restrict__ cursor, int* __restrict__ csr_src,
                            int* __restrict__ csr_eid, int e)
{
    int i = blockIdx.x * 256 + threadIdx.x;
    if (i < e) {
        int pos = atomicAdd(&cursor[dst[i]], 1);
        csr_src[pos] = src[i];
        csr_eid[pos] = i;
    }
}

// ---------------------------------------------------------------------------
// Weighted segment-mean via CSR gather: one wave per node, float2 per lane.
// agg[n,:] = (1/max(deg,1)) * sum_e ew[eid] * h[src_e,:]
// ---------------------------------------------------------------------------
__global__ __launch_bounds__(256) void gather_agg(
    const float* __restrict__ h, const float* __restrict__ ew,
    const int* __restrict__ csr_src, const int* __restrict__ csr_eid,
    const int* __restrict__ off, float* __restrict__ agg, int n_nodes)
{
    int wave = threadIdx.x >> 6;
    int lane = threadIdx.x & 63;
    int node = blockIdx.x * 4 + wave;
    if (node >= n_nodes) return;
    int s0 = off[node], s1 = off[node + 1];
    int c = lane * 2;
    float a0 = 0.f, a1 = 0.f;
    for (int e = s0; e < s1; ++e) {
        int s  = csr_src[e];
        float w = ew[csr_eid[e]];
        float2 hv = *(const float2*)(h + (size_t)s * DIM + c);
        a0 += w * hv.x;
        a1 += w * hv.y;
    }
    float inv = 1.f / fmaxf((float)(s1 - s0), 1.f);
    *(float2*)(agg + (size_t)node * DIM + c) = make_float2(a0 * inv, a1 * inv);
}

// ---------------------------------------------------------------------------
// LSTM elementwise (torch gate order i,f,g,o); final step writes relu(h).
// ---------------------------------------------------------------------------
__global__ void lstm_kernel(const float* __restrict__ gates, float* __restrict__ c,
                            float* __restrict__ h, int total, int last)
{
    int idx = blockIdx.x * 256 + threadIdx.x;
    if (idx >= total) return;
    int n = idx >> 7, d = idx & (DIM - 1);
    const float* g = gates + (size_t)n * 4 * DIM;
    float gi = g[d], gf = g[DIM + d], gg = g[2 * DIM + d], go = g[3 * DIM + d];
    float si = 1.f / (1.f + expf(-gi));
    float sf = 1.f / (1.f + expf(-gf));
    float so = 1.f / (1.f + expf(-go));
    float tg = tanhf(gg);
    float cv = sf * c[idx] + si * tg;
    float hv = so * tanhf(cv);
    c[idx] = cv;
    h[idx] = last ? fmaxf(hv, 0.f) : hv;
}

// ---------------------------------------------------------------------------
extern "C" void kernel_launch(void* const* d_in, const int* in_sizes, int n_in,
                              void* d_out, int out_size, void* d_ws, size_t ws_size,
                              hipStream_t stream)
{
    const float* H     = (const float*)d_in[0];
    const int*   EL    = (const int*)  d_in[1];
    const float* SW    = (const float*)d_in[2];
    const float* Wp    = (const float*)d_in[3];
    const float* bp    = (const float*)d_in[4];
    const float* Wrel  = (const float*)d_in[5];
    const float* Wroot = (const float*)d_in[6];
    const float* Wcomb = (const float*)d_in[7];
    const float* bcomb = (const float*)d_in[8];
    const float* Wpl   = (const float*)d_in[9];
    const float* bpl   = (const float*)d_in[10];
    const float* Wih   = (const float*)d_in[11];
    const float* Whh   = (const float*)d_in[12];
    const float* bih   = (const float*)d_in[13];
    const float* bhh   = (const float*)d_in[14];

    char* wp = (char*)d_ws;
    auto alloc = [&](size_t bytes) {
        char* p = wp;
        wp += (bytes + 255) & ~(size_t)255;
        return p;
    };
    int*   cnt     = (int*)alloc((size_t)NN * 4);
    int*   off     = (int*)alloc((size_t)(NN + 1) * 4);
    int*   cursor  = (int*)alloc((size_t)NN * 4);
    int*   csr_src = (int*)alloc((size_t)EE * 4);
    int*   csr_eid = (int*)alloc((size_t)EE * 4);
    float* hbuf    = (float*)alloc((size_t)NN * DIM * 4);
    float* agg     = (float*)alloc((size_t)NN * DIM * 4);
    float* cvout   = (float*)alloc((size_t)NN * DIM * 4);
    float* proj    = (float*)alloc((size_t)NN * 3 * DIM * 4);
    float* xs      = (float*)alloc((size_t)KH * NN * DIM * 4);
    float* cbuf    = (float*)alloc((size_t)NN * DIM * 4);
    // gates [NN,512] aliases the (dead-after-k-loop) hbuf..proj region (92MB >= 61.5MB)
    float* gates   = hbuf;

    float* hout = (float*)d_out;  // LSTM hidden state lives in d_out

    for (int k = 0; k < KH; ++k) {
        const float* Hk   = H + (size_t)k * NN * DIM;
        const int*   srcp = EL + (size_t)k * 2 * EE;
        const int*   dstp = srcp + EE;

        hipMemsetAsync(cnt, 0, (size_t)NN * 4, stream);
        hist_kernel<<<(EE + 255) / 256, 256, 0, stream>>>(dstp, cnt, EE);
        scan_kernel<<<1, 1024, 0, stream>>>(cnt, off, NN);
        hipMemcpyAsync(cursor, off, (size_t)NN * 4, hipMemcpyDeviceToDevice, stream);
        fill_kernel<<<(EE + 255) / 256, 256, 0, stream>>>(srcp, dstp, cursor, csr_src, csr_eid, EE);

        // proj = b_comb + Hk @ Wcomb[0:128,:]
        gemm(stream, false, false, true, false, Hk, DIM, Wcomb, 3 * DIM, bcomb,
             proj, 3 * DIM, NN, 3 * DIM, DIM);

        for (int i = 0; i < NC; ++i) {
            // h = relu(Hk @ Wp[i] + bp[i])
            gemm(stream, false, false, true, true, Hk, DIM,
                 Wp + (size_t)i * DIM * DIM, DIM, bp + (size_t)i * DIM,
                 hbuf, DIM, NN, DIM, DIM);
            // agg = segment_mean(ew * h[src])
            gather_agg<<<(NN + 3) / 4, 256, 0, stream>>>(
                hbuf, SW + ((size_t)k * NC + i) * EE, csr_src, csr_eid, off, agg, NN);
            // cvout = agg @ Wrel[i] + Hk @ Wroot[i]
            gemm(stream, false, false, false, false, agg, DIM,
                 Wrel + (size_t)i * DIM * DIM, DIM, nullptr, cvout, DIM, NN, DIM, DIM);
            gemm(stream, false, true, false, false, Hk, DIM,
                 Wroot + (size_t)i * DIM * DIM, DIM, nullptr, cvout, DIM, NN, DIM, DIM);
            // proj += cvout @ Wcomb[(i+1)*128 : (i+2)*128, :]; ReLU on last
            gemm(stream, false, true, false, (i == NC - 1), cvout, DIM,
                 Wcomb + (size_t)(i + 1) * DIM * 3 * DIM, 3 * DIM, nullptr,
                 proj, 3 * DIM, NN, 3 * DIM, DIM);
        }
        // xs_k = Hk @ Wpl[0:128,:] + b_pl + proj @ Wpl[128:512,:]
        float* xk = xs + (size_t)k * NN * DIM;
        gemm(stream, false, false, true, false, Hk, DIM, Wpl, DIM, bpl,
             xk, DIM, NN, DIM, DIM);
        gemm(stream, false, true, false, false, proj, 3 * DIM,
             Wpl + (size_t)DIM * DIM, DIM, nullptr, xk, DIM, NN, DIM, 3 * DIM);
    }

    // LSTM over 3 steps; h lives in d_out, c in cbuf.
    hipMemsetAsync(hout, 0, (size_t)NN * DIM * 4, stream);
    hipMemsetAsync(cbuf, 0, (size_t)NN * DIM * 4, stream);
    for (int t = 0; t < KH; ++t) {
        // gates = xs_t @ Wih^T + bih  ;  gates += h @ Whh^T + bhh
        gemm(stream, true, false, true, false, xs + (size_t)t * NN * DIM, DIM,
             Wih, DIM, bih, gates, 4 * DIM, NN, 4 * DIM, DIM);
        gemm(stream, true, true, true, false, hout, DIM,
             Whh, DIM, bhh, gates, 4 * DIM, NN, 4 * DIM, DIM);
        lstm_kernel<<<((NN * DIM) + 255) / 256, 256, 0, stream>>>(
            gates, cbuf, hout, NN * DIM, (t == KH - 1) ? 1 : 0);
    }
}

// Round 2
// 1226.832 us; speedup vs baseline: 3.3324x; 3.3324x over previous
//
#include <hip/hip_runtime.h>
#include <math.h>

constexpr int NN  = 30000;
constexpr int DIM = 128;
constexpr int KH  = 3;
constexpr int NC  = 6;
constexpr int EE  = 480000;

typedef __attribute__((ext_vector_type(8))) short short8;
typedef __attribute__((ext_vector_type(4))) float f32x4;

__device__ __forceinline__ float bflo(unsigned int p) {
    union { unsigned int i; float f; } c; c.i = p << 16; return c.f;
}
__device__ __forceinline__ float bfhi(unsigned int p) {
    union { unsigned int i; float f; } c; c.i = p & 0xffff0000u; return c.f;
}
__device__ __forceinline__ unsigned short f2bf(float f) {
    union { float f; unsigned int i; } c; c.f = f;
    unsigned int u = c.i;
    return (unsigned short)((u + 0x7fffu + ((u >> 16) & 1u)) >> 16);
}
__device__ __forceinline__ float bf2f(unsigned short u) {
    union { unsigned int i; float f; } c; c.i = ((unsigned int)u) << 16; return c.f;
}
__device__ __forceinline__ unsigned int packbf(float x, float y) {
    return (unsigned int)f2bf(x) | ((unsigned int)f2bf(y) << 16);
}

// ---------------------------------------------------------------------------
// bf16 MFMA GEMM: C[M,N] = act( A[M,K] @ B[K,N] + bias ), B given transposed
// as Bt[N,K]. A is split: cols [0,ksplit) from A1 (lda1), rest from A2 (lda2).
// Tile 128x128, 4 waves (2x2 of 64x64), K-step 32, mfma_f32_16x16x32_bf16.
// N must be a multiple of 128, K a multiple of 32, ksplit a multiple of 32.
// ---------------------------------------------------------------------------
template<bool RELU>
__global__ __launch_bounds__(256) void mgemm(
    const unsigned short* __restrict__ A1, int lda1,
    const unsigned short* __restrict__ A2, int lda2, int ksplit,
    const unsigned short* __restrict__ Bt, int ldb,
    const float* __restrict__ bias,
    unsigned short* __restrict__ C, int ldc,
    int M, int K)
{
    __shared__ __align__(16) unsigned char smem[2 * 128 * 80];
    unsigned char* As = smem;
    unsigned char* Bs = smem + 128 * 80;

    const int tid  = threadIdx.x;
    const int lane = tid & 63;
    const int w    = tid >> 6;
    const int wm   = w >> 1, wn = w & 1;
    const int lm   = lane & 15, lg = lane >> 4;
    const int bm   = blockIdx.y * 128;
    const int bn   = blockIdx.x * 128;

    const int srow = tid >> 1;          // 0..127 staged row
    const int shalf= tid & 1;           // which 32B half of the 64B row

    f32x4 acc[4][4] = {};

    int arow = bm + srow; if (arow > M - 1) arow = M - 1;
    const int brow = bn + srow;

    for (int k0 = 0; k0 < K; k0 += 32) {
        const unsigned short* Ap; int la; int kk;
        if (k0 < ksplit) { Ap = A1; la = lda1; kk = k0; }
        else             { Ap = A2; la = lda2; kk = k0 - ksplit; }
        const float4* ga = (const float4*)(Ap + (size_t)arow * la + kk + shalf * 16);
        float4 a0 = ga[0], a1 = ga[1];
        const float4* gb = (const float4*)(Bt + (size_t)brow * ldb + k0 + shalf * 16);
        float4 b0 = gb[0], b1 = gb[1];

        __syncthreads();  // previous iter's frag reads done before overwrite
        *(float4*)(As + srow * 80 + shalf * 32)      = a0;
        *(float4*)(As + srow * 80 + shalf * 32 + 16) = a1;
        *(float4*)(Bs + srow * 80 + shalf * 32)      = b0;
        *(float4*)(Bs + srow * 80 + shalf * 32 + 16) = b1;
        __syncthreads();

        short8 av[4], bv[4];
        #pragma unroll
        for (int f = 0; f < 4; ++f) {
            av[f] = *(const short8*)(As + (wm * 64 + f * 16 + lm) * 80 + lg * 16);
            bv[f] = *(const short8*)(Bs + (wn * 64 + f * 16 + lm) * 80 + lg * 16);
        }
        #pragma unroll
        for (int i = 0; i < 4; ++i)
            #pragma unroll
            for (int j = 0; j < 4; ++j)
                acc[i][j] = __builtin_amdgcn_mfma_f32_16x16x32_bf16(
                    av[i], bv[j], acc[i][j], 0, 0, 0);
    }

    #pragma unroll
    for (int i = 0; i < 4; ++i) {
        int row0 = bm + wm * 64 + i * 16 + lg * 4;
        #pragma unroll
        for (int j = 0; j < 4; ++j) {
            int col = bn + wn * 64 + j * 16 + lm;
            float bb = bias[col];
            #pragma unroll
            for (int r = 0; r < 4; ++r) {
                int row = row0 + r;
                if (row < M) {
                    float v = acc[i][j][r] + bb;
                    if (RELU) v = fmaxf(v, 0.f);
                    C[(size_t)row * ldc + col] = f2bf(v);
                }
            }
        }
    }
}

// ---------------------------------------------------------------------------
// CSR build
// ---------------------------------------------------------------------------
__global__ void hist_kernel(const int* __restrict__ dst, int* __restrict__ cnt, int e)
{
    int i = blockIdx.x * 256 + threadIdx.x;
    if (i < e) atomicAdd(&cnt[dst[i]], 1);
}

__global__ __launch_bounds__(1024) void scan_kernel(const int* __restrict__ cnt,
                                                    int* __restrict__ off, int n)
{
    __shared__ int wsum[16];
    __shared__ int s_carry;
    int lane = threadIdx.x & 63, wid = threadIdx.x >> 6;
    if (threadIdx.x == 0) s_carry = 0;
    __syncthreads();
    for (int base = 0; base < n; base += 1024) {
        int i = base + (int)threadIdx.x;
        int v = (i < n) ? cnt[i] : 0;
        int x = v;
        #pragma unroll
        for (int ofs = 1; ofs < 64; ofs <<= 1) {
            int t = __shfl_up(x, ofs, 64);
            if (lane >= ofs) x += t;
        }
        if (lane == 63) wsum[wid] = x;
        __syncthreads();
        if (wid == 0 && lane < 16) {
            int y = wsum[lane];
            #pragma unroll
            for (int ofs = 1; ofs < 16; ofs <<= 1) {
                int t = __shfl_up(y, ofs, 64);
                if (lane >= ofs) y += t;
            }
            wsum[lane] = y;
        }
        __syncthreads();
        int carry = s_carry;
        int woff  = (wid == 0) ? 0 : wsum[wid - 1];
        if (i < n) off[i] = carry + woff + x - v;   // exclusive
        __syncthreads();
        if (threadIdx.x == 1023) s_carry = carry + wsum[15];
        __syncthreads();
    }
    if (threadIdx.x == 0) off[n] = s_carry;
}

__global__ void fill_kernel(const int* __restrict__ src, const int* __restrict__ dst,
                            int* __restrict__ cursor, int* __restrict__ csr_src,
                            int* __restrict__ csr_eid, int e)
{
    int i = blockIdx.x * 256 + threadIdx.x;
    if (i < e) {
        int pos = atomicAdd(&cursor[dst[i]], 1);
        csr_src[pos] = src[i];
        csr_eid[pos] = i;
    }
}

// ---------------------------------------------------------------------------
// Fused 6-conv weighted segment-mean gather (bf16 in/out, fp32 accum).
// 2 waves per node: half=0 handles convs 0..2, half=1 convs 3..5.
// ---------------------------------------------------------------------------
__global__ __launch_bounds__(256) void gather6(
    const unsigned short* __restrict__ h_all,   // [NN,768]
    const float* __restrict__ sw,               // [6][EE] for this k
    const int* __restrict__ csr_src,
    const int* __restrict__ csr_eid,
    const int* __restrict__ off,
    unsigned short* __restrict__ agg)           // [NN,768]
{
    int wid  = threadIdx.x >> 6;
    int lane = threadIdx.x & 63;
    int node = blockIdx.x * 2 + (wid >> 1);
    int half = wid & 1;
    if (node >= NN) return;
    int s0 = off[node], s1 = off[node + 1];
    float a0 = 0.f, a1 = 0.f, b0 = 0.f, b1 = 0.f, c0 = 0.f, c1 = 0.f;
    const float* sw0 = sw + (size_t)(3 * half) * EE;
    for (int e = s0; e < s1; ++e) {
        int src = csr_src[e];
        int eid = csr_eid[e];
        const unsigned int* hrow =
            (const unsigned int*)(h_all + (size_t)src * 768) + 192 * half + lane;
        float w0 = sw0[eid];
        float w1 = sw0[(size_t)EE + eid];
        float w2 = sw0[2 * (size_t)EE + eid];
        unsigned int p0 = hrow[0];
        unsigned int p1 = hrow[64];
        unsigned int p2 = hrow[128];
        a0 += w0 * bflo(p0); a1 += w0 * bfhi(p0);
        b0 += w1 * bflo(p1); b1 += w1 * bfhi(p1);
        c0 += w2 * bflo(p2); c1 += w2 * bfhi(p2);
    }
    float inv = 1.f / fmaxf((float)(s1 - s0), 1.f);
    unsigned int* orow = (unsigned int*)(agg + (size_t)node * 768) + 192 * half + lane;
    orow[0]   = packbf(a0 * inv, a1 * inv);
    orow[64]  = packbf(b0 * inv, b1 * inv);
    orow[128] = packbf(c0 * inv, c1 * inv);
}

// ---------------------------------------------------------------------------
// fp32 -> bf16 convert of Hk into Y[:,0:128] (pair-packed writes)
// ---------------------------------------------------------------------------
__global__ void cvt_h(const float* __restrict__ Hk, unsigned int* __restrict__ Ypairs,
                      int total)  // total = NN*64
{
    int idx = blockIdx.x * 256 + threadIdx.x;
    if (idx >= total) return;
    int n = idx >> 6, p = idx & 63;
    float2 v = ((const float2*)Hk)[idx];
    Ypairs[(size_t)n * 256 + p] = packbf(v.x, v.y);
}

// ---------------------------------------------------------------------------
// LSTM elementwise (gates bf16 [NN,512] i,f,g,o), c fp32; writes h bf16 or
// final relu(h) fp32.
// ---------------------------------------------------------------------------
__global__ void lstm_ew(const unsigned short* __restrict__ gates,
                        float* __restrict__ c,
                        unsigned short* __restrict__ hnext,
                        float* __restrict__ outp,
                        int total)  // NN*128
{
    int idx = blockIdx.x * 256 + threadIdx.x;
    if (idx >= total) return;
    int n = idx >> 7, d = idx & 127;
    const unsigned short* g = gates + (size_t)n * 512;
    float gi = bf2f(g[d]);
    float gf = bf2f(g[128 + d]);
    float gg = bf2f(g[256 + d]);
    float go = bf2f(g[384 + d]);
    float si = 1.f / (1.f + expf(-gi));
    float sf = 1.f / (1.f + expf(-gf));
    float so = 1.f / (1.f + expf(-go));
    float cv = sf * c[idx] + si * tanhf(gg);
    float hv = so * tanhf(cv);
    c[idx] = cv;
    if (outp) outp[idx] = fmaxf(hv, 0.f);
    else      hnext[idx] = f2bf(hv);
}

// ---------------------------------------------------------------------------
// Weight precompute kernels (run once per launch; all tiny)
// ---------------------------------------------------------------------------
__global__ void wt_wp(const float* __restrict__ Wp, unsigned short* __restrict__ Wp_t)
{
    int idx = blockIdx.x * 256 + threadIdx.x;          // n*128 + k
    if (idx >= NC * DIM * DIM) return;
    int k = idx & 127, n = idx >> 7;
    int i = n >> 7, cc = n & 127;
    Wp_t[idx] = f2bf(Wp[(size_t)i * DIM * DIM + (size_t)k * DIM + cc]);
}

__global__ void wt_full(const float* __restrict__ Wcomb, const float* __restrict__ Wroot,
                        const float* __restrict__ Wrel, unsigned short* __restrict__ Wfull_t)
{
    int idx = blockIdx.x * 256 + threadIdx.x;          // n*896 + m
    if (idx >= 384 * 896) return;
    int m = idx % 896, n = idx / 896;
    float v;
    if (m < 128) {
        v = Wcomb[(size_t)m * 384 + n];
        for (int i = 0; i < NC; ++i) {
            const float* wr = Wroot + (size_t)i * DIM * DIM + (size_t)m * DIM;
            const float* wc = Wcomb + (size_t)(i + 1) * DIM * 384 + n;
            float s = 0.f;
            for (int k = 0; k < DIM; ++k) s += wr[k] * wc[(size_t)k * 384];
            v += s;
        }
    } else {
        int i = (m >> 7) - 1, r = m & 127;
        const float* wr = Wrel + (size_t)i * DIM * DIM + (size_t)r * DIM;
        const float* wc = Wcomb + (size_t)(i + 1) * DIM * 384 + n;
        float s = 0.f;
        for (int k = 0; k < DIM; ++k) s += wr[k] * wc[(size_t)k * 384];
        v = s;
    }
    Wfull_t[idx] = f2bf(v);
}

__global__ void wt_pl(const float* __restrict__ Wpl, unsigned short* __restrict__ Wpl_t)
{
    int idx = blockIdx.x * 256 + threadIdx.x;          // n*512 + k
    if (idx >= 128 * 512) return;
    int k = idx & 511, n = idx >> 9;
    Wpl_t[idx] = f2bf(Wpl[(size_t)k * DIM + n]);
}

__global__ void wt_lstm(const float* __restrict__ Wih, const float* __restrict__ Whh,
                        const float* __restrict__ bih, const float* __restrict__ bhh,
                        unsigned short* __restrict__ Wt, float* __restrict__ bsum)
{
    int idx = blockIdx.x * 256 + threadIdx.x;          // n*256 + k
    if (idx < 512) bsum[idx] = bih[idx] + bhh[idx];
    if (idx >= 512 * 256) return;
    int k = idx & 255, n = idx >> 8;
    Wt[idx] = f2bf(k < 128 ? Wih[(size_t)n * DIM + k]
                           : Whh[(size_t)n * DIM + (k - 128)]);
}

// ---------------------------------------------------------------------------
extern "C" void kernel_launch(void* const* d_in, const int* in_sizes, int n_in,
                              void* d_out, int out_size, void* d_ws, size_t ws_size,
                              hipStream_t stream)
{
    const float* H     = (const float*)d_in[0];
    const int*   EL    = (const int*)  d_in[1];
    const float* SW    = (const float*)d_in[2];
    const float* Wp    = (const float*)d_in[3];
    const float* bp    = (const float*)d_in[4];
    const float* Wrel  = (const float*)d_in[5];
    const float* Wroot = (const float*)d_in[6];
    const float* Wcomb = (const float*)d_in[7];
    const float* bcomb = (const float*)d_in[8];
    const float* Wpl   = (const float*)d_in[9];
    const float* bpl   = (const float*)d_in[10];
    const float* Wih   = (const float*)d_in[11];
    const float* Whh   = (const float*)d_in[12];
    const float* bih   = (const float*)d_in[13];
    const float* bhh   = (const float*)d_in[14];

    char* wp = (char*)d_ws;
    auto alloc = [&](size_t b) {
        char* p = wp; wp += (b + 255) & ~(size_t)255; return p;
    };
    unsigned short* Y     = (unsigned short*)alloc((size_t)NN * 512 * 2); // [Hbf|proj]
    unsigned short* h_all = (unsigned short*)alloc((size_t)NN * 768 * 2); // aliases gates
    unsigned short* agg   = (unsigned short*)alloc((size_t)NN * 768 * 2); // aliases cbuf
    unsigned short* xs    = (unsigned short*)alloc((size_t)KH * NN * 128 * 2);
    unsigned short* hbuf  = (unsigned short*)alloc((size_t)2 * NN * 128 * 2);
    int* cnt     = (int*)alloc((size_t)NN * 4);
    int* off     = (int*)alloc((size_t)(NN + 1) * 4);
    int* cursor  = (int*)alloc((size_t)NN * 4);
    int* csr_src = (int*)alloc((size_t)EE * 4);
    int* csr_eid = (int*)alloc((size_t)EE * 4);
    unsigned short* Wp_t     = (unsigned short*)alloc((size_t)768 * 128 * 2);
    unsigned short* Wfull_t  = (unsigned short*)alloc((size_t)384 * 896 * 2);
    unsigned short* Wpl_t    = (unsigned short*)alloc((size_t)128 * 512 * 2);
    unsigned short* WihWhh_t = (unsigned short*)alloc((size_t)512 * 256 * 2);
    float* bias_lstm         = (float*)alloc(512 * 4);

    unsigned short* gates = h_all;                 // [NN,512] (alias, dead h_all)
    float* cbuf = (float*)agg;                     // [NN,128] fp32 (alias, dead agg)

    // ---- weight precompute ----
    wt_wp  <<<(NC * DIM * DIM + 255) / 256, 256, 0, stream>>>(Wp, Wp_t);
    wt_full<<<(384 * 896 + 255) / 256,     256, 0, stream>>>(Wcomb, Wroot, Wrel, Wfull_t);
    wt_pl  <<<(128 * 512 + 255) / 256,     256, 0, stream>>>(Wpl, Wpl_t);
    wt_lstm<<<(512 * 256 + 255) / 256,     256, 0, stream>>>(Wih, Whh, bih, bhh,
                                                             WihWhh_t, bias_lstm);

    const int MB = (NN + 127) / 128;   // 235 m-blocks

    for (int k = 0; k < KH; ++k) {
        const float* Hk   = H + (size_t)k * NN * DIM;
        const int*   srcp = EL + (size_t)k * 2 * EE;
        const int*   dstp = srcp + EE;

        hipMemsetAsync(cnt, 0, (size_t)NN * 4, stream);
        hist_kernel<<<(EE + 255) / 256, 256, 0, stream>>>(dstp, cnt, EE);
        scan_kernel<<<1, 1024, 0, stream>>>(cnt, off, NN);
        hipMemcpyAsync(cursor, off, (size_t)NN * 4, hipMemcpyDeviceToDevice, stream);
        fill_kernel<<<(EE + 255) / 256, 256, 0, stream>>>(srcp, dstp, cursor,
                                                          csr_src, csr_eid, EE);

        cvt_h<<<(NN * 64 + 255) / 256, 256, 0, stream>>>(Hk, (unsigned int*)Y, NN * 64);

        // h_all = relu(Hbf @ Wp_all + bp)   [NN,768]
        mgemm<true><<<dim3(6, MB), 256, 0, stream>>>(
            Y, 512, (const unsigned short*)nullptr, 0, 128,
            Wp_t, 128, bp, h_all, 768, NN, 128);

        // agg_all = fused weighted segment-mean over 6 convs
        gather6<<<NN / 2, 256, 0, stream>>>(h_all, SW + (size_t)k * NC * EE,
                                            csr_src, csr_eid, off, agg);

        // proj = relu([Hbf|agg] @ Wfull + bcomb) -> Y[:,128:512]
        mgemm<true><<<dim3(3, MB), 256, 0, stream>>>(
            Y, 512, agg, 768, 128,
            Wfull_t, 896, bcomb, Y + 128, 512, NN, 896);

        // xs_k = [Hbf|proj] @ Wpl + bpl   [NN,128]
        mgemm<false><<<dim3(1, MB), 256, 0, stream>>>(
            Y, 512, (const unsigned short*)nullptr, 0, 512,
            Wpl_t, 512, bpl, xs + (size_t)k * NN * 128, 128, NN, 512);
    }

    // ---- LSTM (3 steps) ----
    hipMemsetAsync(hbuf, 0, (size_t)NN * 128 * 2, stream);   // h0 = 0
    hipMemsetAsync(cbuf, 0, (size_t)NN * 128 * 4, stream);   // c0 = 0
    for (int t = 0; t < KH; ++t) {
        unsigned short* hprev = hbuf + (size_t)(t & 1) * NN * 128;
        unsigned short* hnext = hbuf + (size_t)((t + 1) & 1) * NN * 128;
        // gates = [xs_t|h] @ [Wih|Whh]^T + (bih+bhh)   [NN,512]
        mgemm<false><<<dim3(4, MB), 256, 0, stream>>>(
            xs + (size_t)t * NN * 128, 128, hprev, 128, 128,
            WihWhh_t, 256, bias_lstm, gates, 512, NN, 256);
        lstm_ew<<<(NN * 128 + 255) / 256, 256, 0, stream>>>(
            gates, cbuf,
            (t == KH - 1) ? nullptr : hnext,
            (t == KH - 1) ? (float*)d_out : nullptr,
            NN * 128);
    }
}

// Round 3
// 1010.867 us; speedup vs baseline: 4.0443x; 1.2136x over previous
//
#include <hip/hip_runtime.h>
#include <math.h>

constexpr int NN  = 30000;
constexpr int DIM = 128;
constexpr int KH  = 3;
constexpr int NC  = 6;
constexpr int EE  = 480000;
constexpr int NBLK = (NN + 255) / 256;   // 118 scan blocks

typedef __attribute__((ext_vector_type(8))) short short8;
typedef __attribute__((ext_vector_type(4))) float f32x4;
typedef __attribute__((ext_vector_type(2))) float f32x2;

__device__ __forceinline__ unsigned short f2bf(float f) {
    union { float f; unsigned int i; } c; c.f = f;
    unsigned int u = c.i;
    return (unsigned short)((u + 0x7fffu + ((u >> 16) & 1u)) >> 16);
}
__device__ __forceinline__ float bf2f(unsigned int u) {
    union { unsigned int i; float f; } c; c.i = u << 16; return c.f;
}
__device__ __forceinline__ unsigned int packbf(float x, float y) {
    return (unsigned int)f2bf(x) | ((unsigned int)f2bf(y) << 16);
}

// ---------------------------------------------------------------------------
// bf16 MFMA GEMM: C[M,N] = act( A[M,K] @ B[K,N] + bias ), Bt[N,K] transposed.
// A split at ksplit between A1/A2. OUT: 0 = bf16 C, 1 = fp8(e4m3) C.
// 1D grid (nx * ny blocks), XCD-chunked swizzle for A-panel L2 locality.
// ---------------------------------------------------------------------------
template<int OUT, bool RELU>
__global__ __launch_bounds__(256) void mgemm(
    const unsigned short* __restrict__ A1, int lda1,
    const unsigned short* __restrict__ A2, int lda2, int ksplit,
    const unsigned short* __restrict__ Bt, int ldb,
    const float* __restrict__ bias,
    void* __restrict__ Cv, int ldc,
    int M, int K, int nx)
{
    __shared__ __align__(16) unsigned char smem[2 * 128 * 80];
    unsigned char* As = smem;
    unsigned char* Bs = smem + 128 * 80;

    // bijective XCD-chunk swizzle (m204): consecutive logical ids -> same XCD
    const int nwg  = gridDim.x;
    const int orig = blockIdx.x;
    const int q = nwg >> 3, r = nwg & 7;
    const int xcd = orig & 7, idx = orig >> 3;
    const int lin = (xcd < r ? xcd * (q + 1) : r * (q + 1) + (xcd - r) * q) + idx;
    const int bx = lin % nx, by = lin / nx;

    const int tid  = threadIdx.x;
    const int lane = tid & 63;
    const int w    = tid >> 6;
    const int wm   = w >> 1, wn = w & 1;
    const int lm   = lane & 15, lg = lane >> 4;
    const int bm   = by * 128;
    const int bn   = bx * 128;

    const int srow  = tid >> 1;
    const int shalf = tid & 1;

    f32x4 acc[4][4] = {};

    int arow = bm + srow; if (arow > M - 1) arow = M - 1;
    const int brow = bn + srow;

    for (int k0 = 0; k0 < K; k0 += 32) {
        const unsigned short* Ap; int la; int kk;
        if (k0 < ksplit) { Ap = A1; la = lda1; kk = k0; }
        else             { Ap = A2; la = lda2; kk = k0 - ksplit; }
        const float4* ga = (const float4*)(Ap + (size_t)arow * la + kk + shalf * 16);
        float4 a0 = ga[0], a1 = ga[1];
        const float4* gb = (const float4*)(Bt + (size_t)brow * ldb + k0 + shalf * 16);
        float4 b0 = gb[0], b1 = gb[1];

        __syncthreads();
        *(float4*)(As + srow * 80 + shalf * 32)      = a0;
        *(float4*)(As + srow * 80 + shalf * 32 + 16) = a1;
        *(float4*)(Bs + srow * 80 + shalf * 32)      = b0;
        *(float4*)(Bs + srow * 80 + shalf * 32 + 16) = b1;
        __syncthreads();

        short8 av[4], bv[4];
        #pragma unroll
        for (int f = 0; f < 4; ++f) {
            av[f] = *(const short8*)(As + (wm * 64 + f * 16 + lm) * 80 + lg * 16);
            bv[f] = *(const short8*)(Bs + (wn * 64 + f * 16 + lm) * 80 + lg * 16);
        }
        #pragma unroll
        for (int i = 0; i < 4; ++i)
            #pragma unroll
            for (int j = 0; j < 4; ++j)
                acc[i][j] = __builtin_amdgcn_mfma_f32_16x16x32_bf16(
                    av[i], bv[j], acc[i][j], 0, 0, 0);
    }

    #pragma unroll
    for (int i = 0; i < 4; ++i) {
        int row0 = bm + wm * 64 + i * 16 + lg * 4;
        #pragma unroll
        for (int j = 0; j < 4; ++j) {
            int col = bn + wn * 64 + j * 16 + lm;
            float bb = bias[col];
            #pragma unroll
            for (int r = 0; r < 4; ++r) {
                int row = row0 + r;
                if (row < M) {
                    float v = acc[i][j][r] + bb;
                    if (RELU) v = fmaxf(v, 0.f);
                    if (OUT == 0) {
                        ((unsigned short*)Cv)[(size_t)row * ldc + col] = f2bf(v);
                    } else {
                        unsigned int pk = __builtin_amdgcn_cvt_pk_fp8_f32(v, v, 0, false);
                        ((unsigned char*)Cv)[(size_t)row * ldc + col] = (unsigned char)pk;
                    }
                }
            }
        }
    }
}

// ---------------------------------------------------------------------------
// CSR build: hist -> 3-kernel hierarchical scan -> fill (weights packed)
// ---------------------------------------------------------------------------
__global__ void hist_kernel(const int* __restrict__ dst, int* __restrict__ cnt, int e)
{
    int i = blockIdx.x * 256 + threadIdx.x;
    if (i < e) atomicAdd(&cnt[dst[i]], 1);
}

__global__ __launch_bounds__(256) void scan_part(const int* __restrict__ cnt,
                                                 int* __restrict__ off,
                                                 int* __restrict__ bsum, int n)
{
    int lane = threadIdx.x & 63, wid = threadIdx.x >> 6;
    int i = blockIdx.x * 256 + threadIdx.x;
    int v = (i < n) ? cnt[i] : 0;
    int x = v;
    #pragma unroll
    for (int ofs = 1; ofs < 64; ofs <<= 1) {
        int t = __shfl_up(x, ofs, 64);
        if (lane >= ofs) x += t;
    }
    __shared__ int ws[4];
    if (lane == 63) ws[wid] = x;
    __syncthreads();
    int wo = 0;
    for (int j = 0; j < wid; ++j) wo += ws[j];
    if (i < n) off[i] = wo + x - v;                 // block-local exclusive
    if (threadIdx.x == 255) bsum[blockIdx.x] = wo + x;
}

__global__ __launch_bounds__(128) void scan_tops(const int* __restrict__ bsum,
                                                 int* __restrict__ btop, int nb)
{
    __shared__ int buf[128];
    int v = (threadIdx.x < nb) ? bsum[threadIdx.x] : 0;
    buf[threadIdx.x] = v;
    __syncthreads();
    #pragma unroll
    for (int ofs = 1; ofs < 128; ofs <<= 1) {
        int t = (threadIdx.x >= ofs) ? buf[threadIdx.x - ofs] : 0;
        __syncthreads();
        buf[threadIdx.x] += t;
        __syncthreads();
    }
    if (threadIdx.x < nb) btop[threadIdx.x] = buf[threadIdx.x] - v;  // exclusive
}

__global__ __launch_bounds__(256) void scan_add(int* __restrict__ off,
                                                const int* __restrict__ btop,
                                                int* __restrict__ cursor,
                                                int* __restrict__ cnt, int n)
{
    int i = blockIdx.x * 256 + threadIdx.x;
    if (i < n) {
        int o = off[i] + btop[blockIdx.x];
        off[i] = o;
        cursor[i] = o;
        cnt[i] = 0;                                  // ready for next k
    }
    if (blockIdx.x == 0 && threadIdx.x == 0) off[n] = EE;
}

__global__ void fill_kernel(const int* __restrict__ src, const int* __restrict__ dst,
                            const float* __restrict__ sw,
                            int* __restrict__ cursor, int* __restrict__ csr_src,
                            uint2* __restrict__ swp, int e)
{
    int i = blockIdx.x * 256 + threadIdx.x;
    if (i >= e) return;
    int pos = atomicAdd(&cursor[dst[i]], 1);
    csr_src[pos] = src[i];
    uint2 lo, hi;
    lo.x = packbf(sw[i],                   sw[(size_t)EE + i]);
    lo.y = packbf(sw[2 * (size_t)EE + i],  0.f);
    hi.x = packbf(sw[3 * (size_t)EE + i],  sw[4 * (size_t)EE + i]);
    hi.y = packbf(sw[5 * (size_t)EE + i],  0.f);
    swp[(size_t)pos * 2]     = lo;
    swp[(size_t)pos * 2 + 1] = hi;
}

// ---------------------------------------------------------------------------
// Fused 6-conv weighted segment-mean gather. h in fp8 e4m3 [NN,768],
// weights pre-packed in CSR order. 2 waves/node (half = 3 convs each).
// ---------------------------------------------------------------------------
__global__ __launch_bounds__(256) void gather6(
    const unsigned char* __restrict__ h8,
    const uint2* __restrict__ swp,
    const int* __restrict__ csr_src,
    const int* __restrict__ off,
    unsigned short* __restrict__ agg)           // [NN,768] bf16
{
    int wid  = threadIdx.x >> 6;
    int lane = threadIdx.x & 63;
    int node = blockIdx.x * 2 + (wid >> 1);
    int half = wid & 1;
    if (node >= NN) return;
    int s0 = off[node], s1 = off[node + 1];
    float a0 = 0.f, a1 = 0.f, b0 = 0.f, b1 = 0.f, c0 = 0.f, c1 = 0.f;
    for (int e = s0; e < s1; ++e) {
        int src = csr_src[e];
        uint2 wv = swp[(size_t)e * 2 + half];
        float w0 = bf2f(wv.x & 0xffffu);
        float w1 = bf2f(wv.x >> 16);
        float w2 = bf2f(wv.y & 0xffffu);
        const unsigned short* hrow =
            (const unsigned short*)(h8 + (size_t)src * 768 + half * 384) + lane;
        unsigned int p0 = hrow[0];
        unsigned int p1 = hrow[64];
        unsigned int p2 = hrow[128];
        f32x2 h0 = __builtin_amdgcn_cvt_pk_f32_fp8(p0, false);
        f32x2 h1 = __builtin_amdgcn_cvt_pk_f32_fp8(p1, false);
        f32x2 h2 = __builtin_amdgcn_cvt_pk_f32_fp8(p2, false);
        a0 += w0 * h0.x; a1 += w0 * h0.y;
        b0 += w1 * h1.x; b1 += w1 * h1.y;
        c0 += w2 * h2.x; c1 += w2 * h2.y;
    }
    float inv = 1.f / fmaxf((float)(s1 - s0), 1.f);
    unsigned int* orow = (unsigned int*)(agg + (size_t)node * 768) + 192 * half + lane;
    orow[0]   = packbf(a0 * inv, a1 * inv);
    orow[64]  = packbf(b0 * inv, b1 * inv);
    orow[128] = packbf(c0 * inv, c1 * inv);
}

// ---------------------------------------------------------------------------
__global__ void cvt_h(const float* __restrict__ Hk, unsigned int* __restrict__ out,
                      int total)  // total = NN*64 (pairs)
{
    int idx = blockIdx.x * 256 + threadIdx.x;
    if (idx >= total) return;
    float2 v = ((const float2*)Hk)[idx];
    out[idx] = packbf(v.x, v.y);
}

__global__ void lstm_ew(const unsigned short* __restrict__ gates,
                        float* __restrict__ c,
                        unsigned short* __restrict__ hnext,
                        float* __restrict__ outp,
                        int total)
{
    int idx = blockIdx.x * 256 + threadIdx.x;
    if (idx >= total) return;
    int n = idx >> 7, d = idx & 127;
    const unsigned short* g = gates + (size_t)n * 512;
    float gi = bf2f(g[d]);
    float gf = bf2f(g[128 + d]);
    float gg = bf2f(g[256 + d]);
    float go = bf2f(g[384 + d]);
    float si = 1.f / (1.f + expf(-gi));
    float sf = 1.f / (1.f + expf(-gf));
    float so = 1.f / (1.f + expf(-go));
    float cv = sf * c[idx] + si * tanhf(gg);
    float hv = so * tanhf(cv);
    c[idx] = cv;
    if (outp) outp[idx] = fmaxf(hv, 0.f);
    else      hnext[idx] = f2bf(hv);
}

// ---------------------------------------------------------------------------
// Weight precompute (once per launch, tiny)
// ---------------------------------------------------------------------------
__global__ void wt_wp(const float* __restrict__ Wp, unsigned short* __restrict__ Wp_t)
{
    int idx = blockIdx.x * 256 + threadIdx.x;          // n*128 + k
    if (idx >= NC * DIM * DIM) return;
    int k = idx & 127, n = idx >> 7;
    int i = n >> 7, cc = n & 127;
    Wp_t[idx] = f2bf(Wp[(size_t)i * DIM * DIM + (size_t)k * DIM + cc]);
}

__global__ void wt_full(const float* __restrict__ Wcomb, const float* __restrict__ Wroot,
                        const float* __restrict__ Wrel, unsigned short* __restrict__ Wfull_t)
{
    int idx = blockIdx.x * 256 + threadIdx.x;          // n*896 + m
    if (idx >= 384 * 896) return;
    int m = idx % 896, n = idx / 896;
    float v;
    if (m < 128) {
        v = Wcomb[(size_t)m * 384 + n];
        for (int i = 0; i < NC; ++i) {
            const float* wr = Wroot + (size_t)i * DIM * DIM + (size_t)m * DIM;
            const float* wc = Wcomb + (size_t)(i + 1) * DIM * 384 + n;
            float s = 0.f;
            for (int k = 0; k < DIM; ++k) s += wr[k] * wc[(size_t)k * 384];
            v += s;
        }
    } else {
        int i = (m >> 7) - 1, rr = m & 127;
        const float* wr = Wrel + (size_t)i * DIM * DIM + (size_t)rr * DIM;
        const float* wc = Wcomb + (size_t)(i + 1) * DIM * 384 + n;
        float s = 0.f;
        for (int k = 0; k < DIM; ++k) s += wr[k] * wc[(size_t)k * 384];
        v = s;
    }
    Wfull_t[idx] = f2bf(v);
}

__global__ void wt_pl(const float* __restrict__ Wpl, unsigned short* __restrict__ Wpl_t)
{
    int idx = blockIdx.x * 256 + threadIdx.x;          // n*512 + k
    if (idx >= 128 * 512) return;
    int k = idx & 511, n = idx >> 9;
    Wpl_t[idx] = f2bf(Wpl[(size_t)k * DIM + n]);
}

__global__ void wt_lstm(const float* __restrict__ Wih, const float* __restrict__ Whh,
                        const float* __restrict__ bih, const float* __restrict__ bhh,
                        unsigned short* __restrict__ Wt, float* __restrict__ bsum)
{
    int idx = blockIdx.x * 256 + threadIdx.x;          // n*256 + k
    if (idx < 512) bsum[idx] = bih[idx] + bhh[idx];
    if (idx >= 512 * 256) return;
    int k = idx & 255, n = idx >> 8;
    Wt[idx] = f2bf(k < 128 ? Wih[(size_t)n * DIM + k]
                           : Whh[(size_t)n * DIM + (k - 128)]);
}

// ---------------------------------------------------------------------------
extern "C" void kernel_launch(void* const* d_in, const int* in_sizes, int n_in,
                              void* d_out, int out_size, void* d_ws, size_t ws_size,
                              hipStream_t stream)
{
    const float* H     = (const float*)d_in[0];
    const int*   EL    = (const int*)  d_in[1];
    const float* SW    = (const float*)d_in[2];
    const float* Wp    = (const float*)d_in[3];
    const float* bp    = (const float*)d_in[4];
    const float* Wrel  = (const float*)d_in[5];
    const float* Wroot = (const float*)d_in[6];
    const float* Wcomb = (const float*)d_in[7];
    const float* bcomb = (const float*)d_in[8];
    const float* Wpl   = (const float*)d_in[9];
    const float* bpl   = (const float*)d_in[10];
    const float* Wih   = (const float*)d_in[11];
    const float* Whh   = (const float*)d_in[12];
    const float* bih   = (const float*)d_in[13];
    const float* bhh   = (const float*)d_in[14];

    char* wp = (char*)d_ws;
    auto alloc = [&](size_t b) {
        char* p = wp; wp += (b + 255) & ~(size_t)255; return p;
    };
    unsigned short* Hbf  = (unsigned short*)alloc((size_t)NN * 128 * 2);
    unsigned char*  h8   = (unsigned char*) alloc((size_t)NN * 768);      // fp8
    unsigned short* agg  = (unsigned short*)alloc((size_t)NN * 768 * 2);  // aliases gates
    unsigned short* proj = (unsigned short*)alloc((size_t)NN * 384 * 2);
    unsigned short* xs   = (unsigned short*)alloc((size_t)KH * NN * 128 * 2);
    unsigned short* hbuf = (unsigned short*)alloc((size_t)2 * NN * 128 * 2);
    float*          cbuf = (float*)         alloc((size_t)NN * 128 * 4);
    int* cnt     = (int*)alloc((size_t)NN * 4);
    int* off     = (int*)alloc((size_t)(NN + 1) * 4);
    int* cursor  = (int*)alloc((size_t)NN * 4);
    int* bsum    = (int*)alloc((size_t)NBLK * 4);
    int* btop    = (int*)alloc((size_t)NBLK * 4);
    int* csr_src = (int*)alloc((size_t)EE * 4);
    uint2* swp   = (uint2*)alloc((size_t)EE * 16);
    unsigned short* Wp_t     = (unsigned short*)alloc((size_t)768 * 128 * 2);
    unsigned short* Wfull_t  = (unsigned short*)alloc((size_t)384 * 896 * 2);
    unsigned short* Wpl_t    = (unsigned short*)alloc((size_t)128 * 512 * 2);
    unsigned short* WihWhh_t = (unsigned short*)alloc((size_t)512 * 256 * 2);
    float* bias_lstm         = (float*)alloc(512 * 4);

    unsigned short* gates = agg;                  // [NN,512] alias (agg dead)

    // ---- weight precompute ----
    wt_wp  <<<(NC * DIM * DIM + 255) / 256, 256, 0, stream>>>(Wp, Wp_t);
    wt_full<<<(384 * 896 + 255) / 256,     256, 0, stream>>>(Wcomb, Wroot, Wrel, Wfull_t);
    wt_pl  <<<(128 * 512 + 255) / 256,     256, 0, stream>>>(Wpl, Wpl_t);
    wt_lstm<<<(512 * 256 + 255) / 256,     256, 0, stream>>>(Wih, Whh, bih, bhh,
                                                             WihWhh_t, bias_lstm);

    hipMemsetAsync(cnt, 0, (size_t)NN * 4, stream);

    const int MB = (NN + 127) / 128;   // 235

    for (int k = 0; k < KH; ++k) {
        const float* Hk   = H + (size_t)k * NN * DIM;
        const int*   srcp = EL + (size_t)k * 2 * EE;
        const int*   dstp = srcp + EE;

        hist_kernel<<<(EE + 255) / 256, 256, 0, stream>>>(dstp, cnt, EE);
        scan_part<<<NBLK, 256, 0, stream>>>(cnt, off, bsum, NN);
        scan_tops<<<1, 128, 0, stream>>>(bsum, btop, NBLK);
        scan_add<<<NBLK, 256, 0, stream>>>(off, btop, cursor, cnt, NN);
        fill_kernel<<<(EE + 255) / 256, 256, 0, stream>>>(
            srcp, dstp, SW + (size_t)k * NC * EE, cursor, csr_src, swp, EE);

        cvt_h<<<(NN * 64 + 255) / 256, 256, 0, stream>>>(Hk, (unsigned int*)Hbf, NN * 64);

        // h8 = fp8(relu(Hbf @ Wp_all + bp))   [NN,768]
        mgemm<1, true><<<6 * MB, 256, 0, stream>>>(
            Hbf, 128, (const unsigned short*)nullptr, 0, 128,
            Wp_t, 128, bp, h8, 768, NN, 128, 6);

        gather6<<<NN / 2, 256, 0, stream>>>(h8, swp, csr_src, off, agg);

        // proj = relu([Hbf|agg] @ Wfull + bcomb)   [NN,384]
        mgemm<0, true><<<3 * MB, 256, 0, stream>>>(
            Hbf, 128, agg, 768, 128,
            Wfull_t, 896, bcomb, proj, 384, NN, 896, 3);

        // xs_k = [Hbf|proj] @ Wpl + bpl   [NN,128]
        mgemm<0, false><<<1 * MB, 256, 0, stream>>>(
            Hbf, 128, proj, 384, 128,
            Wpl_t, 512, bpl, xs + (size_t)k * NN * 128, 128, NN, 512, 1);
    }

    // ---- LSTM (3 steps) ----
    hipMemsetAsync(hbuf, 0, (size_t)NN * 128 * 2, stream);
    hipMemsetAsync(cbuf, 0, (size_t)NN * 128 * 4, stream);
    for (int t = 0; t < KH; ++t) {
        unsigned short* hprev = hbuf + (size_t)(t & 1) * NN * 128;
        unsigned short* hnext = hbuf + (size_t)((t + 1) & 1) * NN * 128;
        mgemm<0, false><<<4 * MB, 256, 0, stream>>>(
            xs + (size_t)t * NN * 128, 128, hprev, 128, 128,
            WihWhh_t, 256, bias_lstm, gates, 512, NN, 256, 4);
        lstm_ew<<<(NN * 128 + 255) / 256, 256, 0, stream>>>(
            gates, cbuf,
            (t == KH - 1) ? nullptr : hnext,
            (t == KH - 1) ? (float*)d_out : nullptr,
            NN * 128);
    }
}

// Round 4
// 873.434 us; speedup vs baseline: 4.6807x; 1.1573x over previous
//
#include <hip/hip_runtime.h>
#include <math.h>

constexpr int NN  = 30000;
constexpr int DIM = 128;
constexpr int KH  = 3;
constexpr int NC  = 6;
constexpr int EE  = 480000;
constexpr int NBLK = (NN + 255) / 256;   // 118 scan blocks

typedef __attribute__((ext_vector_type(8))) short short8;
typedef __attribute__((ext_vector_type(4))) float f32x4;
typedef __attribute__((ext_vector_type(2))) float f32x2;

__device__ __forceinline__ unsigned short f2bf(float f) {
    union { float f; unsigned int i; } c; c.f = f;
    unsigned int u = c.i;
    return (unsigned short)((u + 0x7fffu + ((u >> 16) & 1u)) >> 16);
}
__device__ __forceinline__ float bf2f(unsigned int u) {
    union { unsigned int i; float f; } c; c.i = u << 16; return c.f;
}
__device__ __forceinline__ unsigned int packbf(float x, float y) {
    return (unsigned int)f2bf(x) | ((unsigned int)f2bf(y) << 16);
}

// ---------------------------------------------------------------------------
// bf16 MFMA GEMM: C[M,N] = act( A[M,K] @ B[K,N] + bias ), Bt[N,K] transposed.
// A split at ksplit between A1/A2. OUT: 0 = bf16 C, 1 = fp8(e4m3) C.
// 1D grid, XCD-chunked bijective swizzle for A-panel L2 locality.
// ---------------------------------------------------------------------------
template<int OUT, bool RELU>
__global__ __launch_bounds__(256) void mgemm(
    const unsigned short* __restrict__ A1, int lda1,
    const unsigned short* __restrict__ A2, int lda2, int ksplit,
    const unsigned short* __restrict__ Bt, int ldb,
    const float* __restrict__ bias,
    void* __restrict__ Cv, int ldc,
    int M, int K, int nx)
{
    __shared__ __align__(16) unsigned char smem[2 * 128 * 80];
    unsigned char* As = smem;
    unsigned char* Bs = smem + 128 * 80;

    const int nwg  = gridDim.x;
    const int orig = blockIdx.x;
    const int q = nwg >> 3, r = nwg & 7;
    const int xcd = orig & 7, idx = orig >> 3;
    const int lin = (xcd < r ? xcd * (q + 1) : r * (q + 1) + (xcd - r) * q) + idx;
    const int bx = lin % nx, by = lin / nx;

    const int tid  = threadIdx.x;
    const int lane = tid & 63;
    const int w    = tid >> 6;
    const int wm   = w >> 1, wn = w & 1;
    const int lm   = lane & 15, lg = lane >> 4;
    const int bm   = by * 128;
    const int bn   = bx * 128;

    const int srow  = tid >> 1;
    const int shalf = tid & 1;

    f32x4 acc[4][4] = {};

    int arow = bm + srow; if (arow > M - 1) arow = M - 1;
    const int brow = bn + srow;

    for (int k0 = 0; k0 < K; k0 += 32) {
        const unsigned short* Ap; int la; int kk;
        if (k0 < ksplit) { Ap = A1; la = lda1; kk = k0; }
        else             { Ap = A2; la = lda2; kk = k0 - ksplit; }
        const float4* ga = (const float4*)(Ap + (size_t)arow * la + kk + shalf * 16);
        float4 a0 = ga[0], a1 = ga[1];
        const float4* gb = (const float4*)(Bt + (size_t)brow * ldb + k0 + shalf * 16);
        float4 b0 = gb[0], b1 = gb[1];

        __syncthreads();
        *(float4*)(As + srow * 80 + shalf * 32)      = a0;
        *(float4*)(As + srow * 80 + shalf * 32 + 16) = a1;
        *(float4*)(Bs + srow * 80 + shalf * 32)      = b0;
        *(float4*)(Bs + srow * 80 + shalf * 32 + 16) = b1;
        __syncthreads();

        short8 av[4], bv[4];
        #pragma unroll
        for (int f = 0; f < 4; ++f) {
            av[f] = *(const short8*)(As + (wm * 64 + f * 16 + lm) * 80 + lg * 16);
            bv[f] = *(const short8*)(Bs + (wn * 64 + f * 16 + lm) * 80 + lg * 16);
        }
        #pragma unroll
        for (int i = 0; i < 4; ++i)
            #pragma unroll
            for (int j = 0; j < 4; ++j)
                acc[i][j] = __builtin_amdgcn_mfma_f32_16x16x32_bf16(
                    av[i], bv[j], acc[i][j], 0, 0, 0);
    }

    #pragma unroll
    for (int i = 0; i < 4; ++i) {
        int row0 = bm + wm * 64 + i * 16 + lg * 4;
        #pragma unroll
        for (int j = 0; j < 4; ++j) {
            int col = bn + wn * 64 + j * 16 + lm;
            float bb = bias[col];
            #pragma unroll
            for (int r = 0; r < 4; ++r) {
                int row = row0 + r;
                if (row < M) {
                    float v = acc[i][j][r] + bb;
                    if (RELU) v = fmaxf(v, 0.f);
                    if (OUT == 0) {
                        ((unsigned short*)Cv)[(size_t)row * ldc + col] = f2bf(v);
                    } else {
                        unsigned int pk = __builtin_amdgcn_cvt_pk_fp8_f32(v, v, 0, false);
                        ((unsigned char*)Cv)[(size_t)row * ldc + col] = (unsigned char)pk;
                    }
                }
            }
        }
    }
}

// ---------------------------------------------------------------------------
// CSR build
// ---------------------------------------------------------------------------
__global__ void hist_kernel(const int* __restrict__ dst, int* __restrict__ cnt, int e)
{
    int i = blockIdx.x * 256 + threadIdx.x;
    if (i < e) atomicAdd(&cnt[dst[i]], 1);
}

__global__ __launch_bounds__(256) void scan_part(const int* __restrict__ cnt,
                                                 int* __restrict__ off,
                                                 int* __restrict__ bsum, int n)
{
    int lane = threadIdx.x & 63, wid = threadIdx.x >> 6;
    int i = blockIdx.x * 256 + threadIdx.x;
    int v = (i < n) ? cnt[i] : 0;
    int x = v;
    #pragma unroll
    for (int ofs = 1; ofs < 64; ofs <<= 1) {
        int t = __shfl_up(x, ofs, 64);
        if (lane >= ofs) x += t;
    }
    __shared__ int ws[4];
    if (lane == 63) ws[wid] = x;
    __syncthreads();
    int wo = 0;
    for (int j = 0; j < wid; ++j) wo += ws[j];
    if (i < n) off[i] = wo + x - v;
    if (threadIdx.x == 255) bsum[blockIdx.x] = wo + x;
}

__global__ __launch_bounds__(128) void scan_tops(const int* __restrict__ bsum,
                                                 int* __restrict__ btop, int nb)
{
    __shared__ int buf[128];
    int v = (threadIdx.x < nb) ? bsum[threadIdx.x] : 0;
    buf[threadIdx.x] = v;
    __syncthreads();
    #pragma unroll
    for (int ofs = 1; ofs < 128; ofs <<= 1) {
        int t = (threadIdx.x >= ofs) ? buf[threadIdx.x - ofs] : 0;
        __syncthreads();
        buf[threadIdx.x] += t;
        __syncthreads();
    }
    if (threadIdx.x < nb) btop[threadIdx.x] = buf[threadIdx.x] - v;
}

__global__ __launch_bounds__(256) void scan_add(int* __restrict__ off,
                                                const int* __restrict__ btop,
                                                int* __restrict__ cursor,
                                                int* __restrict__ cnt, int n)
{
    int i = blockIdx.x * 256 + threadIdx.x;
    if (i < n) {
        int o = off[i] + btop[blockIdx.x];
        off[i] = o;
        cursor[i] = o;
        cnt[i] = 0;
    }
    if (blockIdx.x == 0 && threadIdx.x == 0) off[n] = EE;
}

__global__ void fill_kernel(const int* __restrict__ src, const int* __restrict__ dst,
                            const float* __restrict__ sw,
                            int* __restrict__ cursor, int* __restrict__ csr_src,
                            uint2* __restrict__ swp, int e)
{
    int i = blockIdx.x * 256 + threadIdx.x;
    if (i >= e) return;
    int pos = atomicAdd(&cursor[dst[i]], 1);
    csr_src[pos] = src[i];
    uint2 lo, hi;
    lo.x = packbf(sw[i],                   sw[(size_t)EE + i]);
    lo.y = packbf(sw[2 * (size_t)EE + i],  0.f);
    hi.x = packbf(sw[3 * (size_t)EE + i],  sw[4 * (size_t)EE + i]);
    hi.y = packbf(sw[5 * (size_t)EE + i],  0.f);
    swp[(size_t)pos * 2]     = lo;
    swp[(size_t)pos * 2 + 1] = hi;
}

// ---------------------------------------------------------------------------
// Fused 6-conv weighted segment-mean gather, unroll-4 software pipeline.
// ---------------------------------------------------------------------------
__global__ __launch_bounds__(256) void gather6(
    const unsigned char* __restrict__ h8,
    const uint2* __restrict__ swp,
    const int* __restrict__ csr_src,
    const int* __restrict__ off,
    unsigned short* __restrict__ agg)
{
    int wid  = threadIdx.x >> 6;
    int lane = threadIdx.x & 63;
    int node = blockIdx.x * 2 + (wid >> 1);
    int half = wid & 1;
    if (node >= NN) return;
    int s0 = off[node], s1 = off[node + 1];
    float a0 = 0.f, a1 = 0.f, b0 = 0.f, b1 = 0.f, c0 = 0.f, c1 = 0.f;
    const size_t hofs = (size_t)half * 384 + (size_t)lane * 2;

    int e = s0;
    for (; e + 3 < s1; e += 4) {
        int sA = csr_src[e],     sB = csr_src[e + 1];
        int sC = csr_src[e + 2], sD = csr_src[e + 3];
        uint2 wA = swp[(size_t)(e    ) * 2 + half];
        uint2 wB = swp[(size_t)(e + 1) * 2 + half];
        uint2 wC = swp[(size_t)(e + 2) * 2 + half];
        uint2 wD = swp[(size_t)(e + 3) * 2 + half];
        const unsigned short* rA = (const unsigned short*)(h8 + (size_t)sA * 768 + hofs);
        const unsigned short* rB = (const unsigned short*)(h8 + (size_t)sB * 768 + hofs);
        const unsigned short* rC = (const unsigned short*)(h8 + (size_t)sC * 768 + hofs);
        const unsigned short* rD = (const unsigned short*)(h8 + (size_t)sD * 768 + hofs);
        unsigned int pA0 = rA[0], pA1 = rA[64], pA2 = rA[128];
        unsigned int pB0 = rB[0], pB1 = rB[64], pB2 = rB[128];
        unsigned int pC0 = rC[0], pC1 = rC[64], pC2 = rC[128];
        unsigned int pD0 = rD[0], pD1 = rD[64], pD2 = rD[128];

        {
            float w0 = bf2f(wA.x & 0xffffu), w1 = bf2f(wA.x >> 16), w2 = bf2f(wA.y & 0xffffu);
            f32x2 h0 = __builtin_amdgcn_cvt_pk_f32_fp8(pA0, false);
            f32x2 h1 = __builtin_amdgcn_cvt_pk_f32_fp8(pA1, false);
            f32x2 h2 = __builtin_amdgcn_cvt_pk_f32_fp8(pA2, false);
            a0 += w0 * h0.x; a1 += w0 * h0.y;
            b0 += w1 * h1.x; b1 += w1 * h1.y;
            c0 += w2 * h2.x; c1 += w2 * h2.y;
        }
        {
            float w0 = bf2f(wB.x & 0xffffu), w1 = bf2f(wB.x >> 16), w2 = bf2f(wB.y & 0xffffu);
            f32x2 h0 = __builtin_amdgcn_cvt_pk_f32_fp8(pB0, false);
            f32x2 h1 = __builtin_amdgcn_cvt_pk_f32_fp8(pB1, false);
            f32x2 h2 = __builtin_amdgcn_cvt_pk_f32_fp8(pB2, false);
            a0 += w0 * h0.x; a1 += w0 * h0.y;
            b0 += w1 * h1.x; b1 += w1 * h1.y;
            c0 += w2 * h2.x; c1 += w2 * h2.y;
        }
        {
            float w0 = bf2f(wC.x & 0xffffu), w1 = bf2f(wC.x >> 16), w2 = bf2f(wC.y & 0xffffu);
            f32x2 h0 = __builtin_amdgcn_cvt_pk_f32_fp8(pC0, false);
            f32x2 h1 = __builtin_amdgcn_cvt_pk_f32_fp8(pC1, false);
            f32x2 h2 = __builtin_amdgcn_cvt_pk_f32_fp8(pC2, false);
            a0 += w0 * h0.x; a1 += w0 * h0.y;
            b0 += w1 * h1.x; b1 += w1 * h1.y;
            c0 += w2 * h2.x; c1 += w2 * h2.y;
        }
        {
            float w0 = bf2f(wD.x & 0xffffu), w1 = bf2f(wD.x >> 16), w2 = bf2f(wD.y & 0xffffu);
            f32x2 h0 = __builtin_amdgcn_cvt_pk_f32_fp8(pD0, false);
            f32x2 h1 = __builtin_amdgcn_cvt_pk_f32_fp8(pD1, false);
            f32x2 h2 = __builtin_amdgcn_cvt_pk_f32_fp8(pD2, false);
            a0 += w0 * h0.x; a1 += w0 * h0.y;
            b0 += w1 * h1.x; b1 += w1 * h1.y;
            c0 += w2 * h2.x; c1 += w2 * h2.y;
        }
    }
    for (; e < s1; ++e) {
        int src = csr_src[e];
        uint2 wv = swp[(size_t)e * 2 + half];
        float w0 = bf2f(wv.x & 0xffffu);
        float w1 = bf2f(wv.x >> 16);
        float w2 = bf2f(wv.y & 0xffffu);
        const unsigned short* hrow = (const unsigned short*)(h8 + (size_t)src * 768 + hofs);
        unsigned int p0 = hrow[0];
        unsigned int p1 = hrow[64];
        unsigned int p2 = hrow[128];
        f32x2 h0 = __builtin_amdgcn_cvt_pk_f32_fp8(p0, false);
        f32x2 h1 = __builtin_amdgcn_cvt_pk_f32_fp8(p1, false);
        f32x2 h2 = __builtin_amdgcn_cvt_pk_f32_fp8(p2, false);
        a0 += w0 * h0.x; a1 += w0 * h0.y;
        b0 += w1 * h1.x; b1 += w1 * h1.y;
        c0 += w2 * h2.x; c1 += w2 * h2.y;
    }
    float inv = 1.f / fmaxf((float)(s1 - s0), 1.f);
    unsigned int* orow = (unsigned int*)(agg + (size_t)node * 768) + 192 * half + lane;
    orow[0]   = packbf(a0 * inv, a1 * inv);
    orow[64]  = packbf(b0 * inv, b1 * inv);
    orow[128] = packbf(c0 * inv, c1 * inv);
}

// ---------------------------------------------------------------------------
__global__ void cvt_h(const float* __restrict__ Hk, unsigned int* __restrict__ out,
                      int total)
{
    int idx = blockIdx.x * 256 + threadIdx.x;
    if (idx >= total) return;
    float2 v = ((const float2*)Hk)[idx];
    out[idx] = packbf(v.x, v.y);
}

// ---------------------------------------------------------------------------
// Fused 3-step LSTM. Block = 64 nodes, 256 threads (4 waves).
// A-LDS [64][256 shorts] = [xs_t | h], XOR-swizzled 16B granules.
// Gates in LDS (bf16, stride 520 shorts); c in registers (32/thread).
// Wave w computes gate chunk [w*128, w*128+128) via MFMA, 2 halves of 64 cols.
// ---------------------------------------------------------------------------
#define SWA(r, b) ((r) * 512 + ((b) ^ (((r) & 7) << 4)))

__global__ __launch_bounds__(256) void lstm_fused(
    const unsigned short* __restrict__ xs,   // [3][NN][128]
    const unsigned short* __restrict__ Wt,   // [512][256]
    const float* __restrict__ bsum,          // [512]
    float* __restrict__ outp)                // [NN][128]
{
    __shared__ __align__(16) unsigned char AL[64 * 512];
    __shared__ __align__(16) unsigned short GL[64 * 520];

    const int tid  = threadIdx.x;
    const int lane = tid & 63;
    const int w    = tid >> 6;
    const int lm   = lane & 15, lg = lane >> 4;
    const int node0 = blockIdx.x * 64;
    const int gbase = w * 128;

    float creg[32];
    #pragma unroll
    for (int j = 0; j < 32; ++j) creg[j] = 0.f;

    // zero h half of A
    float4 z4 = make_float4(0.f, 0.f, 0.f, 0.f);
    for (int qq = tid; qq < 64 * 16; qq += 256) {
        int r = qq >> 4, gi = qq & 15;
        *(float4*)(AL + SWA(r, 256 + gi * 16)) = z4;
    }

    for (int t = 0; t < KH; ++t) {
        // stage xs_t
        const unsigned short* xsrc = xs + (size_t)t * NN * 128;
        for (int qq = tid; qq < 64 * 16; qq += 256) {
            int r = qq >> 4, gi = qq & 15;
            int gr = node0 + r; if (gr >= NN) gr = NN - 1;
            float4 v = *(const float4*)(xsrc + (size_t)gr * 128 + gi * 8);
            *(float4*)(AL + SWA(r, gi * 16)) = v;
        }
        __syncthreads();

        #pragma unroll
        for (int nh = 0; nh < 2; ++nh) {
            f32x4 acc[4][4] = {};
            #pragma unroll
            for (int ks = 0; ks < 8; ++ks) {
                short8 av[4], bv[4];
                #pragma unroll
                for (int i = 0; i < 4; ++i)
                    av[i] = *(const short8*)(AL + SWA(i * 16 + lm, ks * 64 + lg * 16));
                #pragma unroll
                for (int j = 0; j < 4; ++j)
                    bv[j] = *(const short8*)(Wt +
                        (size_t)(gbase + nh * 64 + j * 16 + lm) * 256 + ks * 32 + lg * 8);
                #pragma unroll
                for (int i = 0; i < 4; ++i)
                    #pragma unroll
                    for (int j = 0; j < 4; ++j)
                        acc[i][j] = __builtin_amdgcn_mfma_f32_16x16x32_bf16(
                            av[i], bv[j], acc[i][j], 0, 0, 0);
            }
            #pragma unroll
            for (int i = 0; i < 4; ++i)
                #pragma unroll
                for (int j = 0; j < 4; ++j)
                    #pragma unroll
                    for (int r = 0; r < 4; ++r)
                        GL[(i * 16 + lg * 4 + r) * 520 + gbase + nh * 64 + j * 16 + lm] =
                            f2bf(acc[i][j][r]);
        }
        __syncthreads();

        // elementwise
        #pragma unroll
        for (int jj = 0; jj < 32; ++jj) {
            int idx = jj * 256 + tid;
            int n = idx >> 7, d = idx & 127;
            float gi_ = bf2f(GL[n * 520 + d])        + bsum[d];
            float gf_ = bf2f(GL[n * 520 + 128 + d])  + bsum[128 + d];
            float gg_ = bf2f(GL[n * 520 + 256 + d])  + bsum[256 + d];
            float go_ = bf2f(GL[n * 520 + 384 + d])  + bsum[384 + d];
            float si = 1.f / (1.f + expf(-gi_));
            float sf = 1.f / (1.f + expf(-gf_));
            float so = 1.f / (1.f + expf(-go_));
            float cv = sf * creg[jj] + si * tanhf(gg_);
            creg[jj] = cv;
            float hv = so * tanhf(cv);
            if (t < KH - 1) {
                *(unsigned short*)(AL + SWA(n, 256 + 2 * d)) = f2bf(hv);
            } else if (node0 + n < NN) {
                outp[(size_t)(node0 + n) * 128 + d] = fmaxf(hv, 0.f);
            }
        }
        __syncthreads();
    }
}

// ---------------------------------------------------------------------------
// Weight precompute (once per launch, tiny)
// ---------------------------------------------------------------------------
__global__ void wt_wp(const float* __restrict__ Wp, unsigned short* __restrict__ Wp_t)
{
    int idx = blockIdx.x * 256 + threadIdx.x;
    if (idx >= NC * DIM * DIM) return;
    int k = idx & 127, n = idx >> 7;
    int i = n >> 7, cc = n & 127;
    Wp_t[idx] = f2bf(Wp[(size_t)i * DIM * DIM + (size_t)k * DIM + cc]);
}

__global__ void wt_full(const float* __restrict__ Wcomb, const float* __restrict__ Wroot,
                        const float* __restrict__ Wrel, unsigned short* __restrict__ Wfull_t)
{
    int idx = blockIdx.x * 256 + threadIdx.x;
    if (idx >= 384 * 896) return;
    int m = idx % 896, n = idx / 896;
    float v;
    if (m < 128) {
        v = Wcomb[(size_t)m * 384 + n];
        for (int i = 0; i < NC; ++i) {
            const float* wr = Wroot + (size_t)i * DIM * DIM + (size_t)m * DIM;
            const float* wc = Wcomb + (size_t)(i + 1) * DIM * 384 + n;
            float s = 0.f;
            for (int k = 0; k < DIM; ++k) s += wr[k] * wc[(size_t)k * 384];
            v += s;
        }
    } else {
        int i = (m >> 7) - 1, rr = m & 127;
        const float* wr = Wrel + (size_t)i * DIM * DIM + (size_t)rr * DIM;
        const float* wc = Wcomb + (size_t)(i + 1) * DIM * 384 + n;
        float s = 0.f;
        for (int k = 0; k < DIM; ++k) s += wr[k] * wc[(size_t)k * 384];
        v = s;
    }
    Wfull_t[idx] = f2bf(v);
}

__global__ void wt_pl(const float* __restrict__ Wpl, unsigned short* __restrict__ Wpl_t)
{
    int idx = blockIdx.x * 256 + threadIdx.x;
    if (idx >= 128 * 512) return;
    int k = idx & 511, n = idx >> 9;
    Wpl_t[idx] = f2bf(Wpl[(size_t)k * DIM + n]);
}

__global__ void wt_lstm(const float* __restrict__ Wih, const float* __restrict__ Whh,
                        const float* __restrict__ bih, const float* __restrict__ bhh,
                        unsigned short* __restrict__ Wt, float* __restrict__ bsum)
{
    int idx = blockIdx.x * 256 + threadIdx.x;
    if (idx < 512) bsum[idx] = bih[idx] + bhh[idx];
    if (idx >= 512 * 256) return;
    int k = idx & 255, n = idx >> 8;
    Wt[idx] = f2bf(k < 128 ? Wih[(size_t)n * DIM + k]
                           : Whh[(size_t)n * DIM + (k - 128)]);
}

// ---------------------------------------------------------------------------
extern "C" void kernel_launch(void* const* d_in, const int* in_sizes, int n_in,
                              void* d_out, int out_size, void* d_ws, size_t ws_size,
                              hipStream_t stream)
{
    const float* H     = (const float*)d_in[0];
    const int*   EL    = (const int*)  d_in[1];
    const float* SW    = (const float*)d_in[2];
    const float* Wp    = (const float*)d_in[3];
    const float* bp    = (const float*)d_in[4];
    const float* Wrel  = (const float*)d_in[5];
    const float* Wroot = (const float*)d_in[6];
    const float* Wcomb = (const float*)d_in[7];
    const float* bcomb = (const float*)d_in[8];
    const float* Wpl   = (const float*)d_in[9];
    const float* bpl   = (const float*)d_in[10];
    const float* Wih   = (const float*)d_in[11];
    const float* Whh   = (const float*)d_in[12];
    const float* bih   = (const float*)d_in[13];
    const float* bhh   = (const float*)d_in[14];

    char* wp = (char*)d_ws;
    auto alloc = [&](size_t b) {
        char* p = wp; wp += (b + 255) & ~(size_t)255; return p;
    };
    unsigned short* Hbf  = (unsigned short*)alloc((size_t)NN * 128 * 2);
    unsigned char*  h8   = (unsigned char*) alloc((size_t)NN * 768);
    unsigned short* agg  = (unsigned short*)alloc((size_t)NN * 768 * 2);
    unsigned short* proj = (unsigned short*)alloc((size_t)NN * 384 * 2);
    unsigned short* xs   = (unsigned short*)alloc((size_t)KH * NN * 128 * 2);
    int* cnt     = (int*)alloc((size_t)NN * 4);
    int* off     = (int*)alloc((size_t)(NN + 1) * 4);
    int* cursor  = (int*)alloc((size_t)NN * 4);
    int* bsum    = (int*)alloc((size_t)NBLK * 4);
    int* btop    = (int*)alloc((size_t)NBLK * 4);
    int* csr_src = (int*)alloc((size_t)EE * 4);
    uint2* swp   = (uint2*)alloc((size_t)EE * 16);
    unsigned short* Wp_t     = (unsigned short*)alloc((size_t)768 * 128 * 2);
    unsigned short* Wfull_t  = (unsigned short*)alloc((size_t)384 * 896 * 2);
    unsigned short* Wpl_t    = (unsigned short*)alloc((size_t)128 * 512 * 2);
    unsigned short* WihWhh_t = (unsigned short*)alloc((size_t)512 * 256 * 2);
    float* bias_lstm         = (float*)alloc(512 * 4);

    // ---- weight precompute ----
    wt_wp  <<<(NC * DIM * DIM + 255) / 256, 256, 0, stream>>>(Wp, Wp_t);
    wt_full<<<(384 * 896 + 255) / 256,     256, 0, stream>>>(Wcomb, Wroot, Wrel, Wfull_t);
    wt_pl  <<<(128 * 512 + 255) / 256,     256, 0, stream>>>(Wpl, Wpl_t);
    wt_lstm<<<(512 * 256 + 255) / 256,     256, 0, stream>>>(Wih, Whh, bih, bhh,
                                                             WihWhh_t, bias_lstm);

    hipMemsetAsync(cnt, 0, (size_t)NN * 4, stream);

    const int MB = (NN + 127) / 128;   // 235

    for (int k = 0; k < KH; ++k) {
        const float* Hk   = H + (size_t)k * NN * DIM;
        const int*   srcp = EL + (size_t)k * 2 * EE;
        const int*   dstp = srcp + EE;

        hist_kernel<<<(EE + 255) / 256, 256, 0, stream>>>(dstp, cnt, EE);
        scan_part<<<NBLK, 256, 0, stream>>>(cnt, off, bsum, NN);
        scan_tops<<<1, 128, 0, stream>>>(bsum, btop, NBLK);
        scan_add<<<NBLK, 256, 0, stream>>>(off, btop, cursor, cnt, NN);
        fill_kernel<<<(EE + 255) / 256, 256, 0, stream>>>(
            srcp, dstp, SW + (size_t)k * NC * EE, cursor, csr_src, swp, EE);

        cvt_h<<<(NN * 64 + 255) / 256, 256, 0, stream>>>(Hk, (unsigned int*)Hbf, NN * 64);

        // h8 = fp8(relu(Hbf @ Wp_all + bp))   [NN,768]
        mgemm<1, true><<<6 * MB, 256, 0, stream>>>(
            Hbf, 128, (const unsigned short*)nullptr, 0, 128,
            Wp_t, 128, bp, h8, 768, NN, 128, 6);

        gather6<<<NN / 2, 256, 0, stream>>>(h8, swp, csr_src, off, agg);

        // proj = relu([Hbf|agg] @ Wfull + bcomb)   [NN,384]
        mgemm<0, true><<<3 * MB, 256, 0, stream>>>(
            Hbf, 128, agg, 768, 128,
            Wfull_t, 896, bcomb, proj, 384, NN, 896, 3);

        // xs_k = [Hbf|proj] @ Wpl + bpl   [NN,128]
        mgemm<0, false><<<1 * MB, 256, 0, stream>>>(
            Hbf, 128, proj, 384, 128,
            Wpl_t, 512, bpl, xs + (size_t)k * NN * 128, 128, NN, 512, 1);
    }

    // ---- fused LSTM ----
    lstm_fused<<<(NN + 63) / 64, 256, 0, stream>>>(xs, WihWhh_t, bias_lstm,
                                                   (float*)d_out);
}

// Round 5
// 857.786 us; speedup vs baseline: 4.7660x; 1.0182x over previous
//
#include <hip/hip_runtime.h>
#include <math.h>

constexpr int NN  = 30000;
constexpr int DIM = 128;
constexpr int KH  = 3;
constexpr int NC  = 6;
constexpr int EE  = 480000;
constexpr int NBLK = (NN + 255) / 256;   // 118 scan blocks

typedef __attribute__((ext_vector_type(8))) short short8;
typedef __attribute__((ext_vector_type(4))) float f32x4;
typedef __attribute__((ext_vector_type(2))) float f32x2;

__device__ __forceinline__ unsigned short f2bf(float f) {
    union { float f; unsigned int i; } c; c.f = f;
    unsigned int u = c.i;
    return (unsigned short)((u + 0x7fffu + ((u >> 16) & 1u)) >> 16);
}
__device__ __forceinline__ float bf2f(unsigned int u) {
    union { unsigned int i; float f; } c; c.i = u << 16; return c.f;
}
__device__ __forceinline__ unsigned int packbf(float x, float y) {
    return (unsigned int)f2bf(x) | ((unsigned int)f2bf(y) << 16);
}

// ---------------------------------------------------------------------------
// bf16 MFMA GEMM: C[M,N] = act( A[M,K] @ B[K,N] + bias ), Bt[N,K] transposed.
// A split at ksplit between A1/A2. OUT: 0 = bf16 C, 1 = fp8(e4m3) C.
// 1D grid, XCD-chunked bijective swizzle for A-panel L2 locality.
// ---------------------------------------------------------------------------
template<int OUT, bool RELU>
__global__ __launch_bounds__(256) void mgemm(
    const unsigned short* __restrict__ A1, int lda1,
    const unsigned short* __restrict__ A2, int lda2, int ksplit,
    const unsigned short* __restrict__ Bt, int ldb,
    const float* __restrict__ bias,
    void* __restrict__ Cv, int ldc,
    int M, int K, int nx)
{
    __shared__ __align__(16) unsigned char smem[2 * 128 * 80];
    unsigned char* As = smem;
    unsigned char* Bs = smem + 128 * 80;

    const int nwg  = gridDim.x;
    const int orig = blockIdx.x;
    const int q = nwg >> 3, r = nwg & 7;
    const int xcd = orig & 7, idx = orig >> 3;
    const int lin = (xcd < r ? xcd * (q + 1) : r * (q + 1) + (xcd - r) * q) + idx;
    const int bx = lin % nx, by = lin / nx;

    const int tid  = threadIdx.x;
    const int lane = tid & 63;
    const int w    = tid >> 6;
    const int wm   = w >> 1, wn = w & 1;
    const int lm   = lane & 15, lg = lane >> 4;
    const int bm   = by * 128;
    const int bn   = bx * 128;

    const int srow  = tid >> 1;
    const int shalf = tid & 1;

    f32x4 acc[4][4] = {};

    int arow = bm + srow; if (arow > M - 1) arow = M - 1;
    const int brow = bn + srow;

    for (int k0 = 0; k0 < K; k0 += 32) {
        const unsigned short* Ap; int la; int kk;
        if (k0 < ksplit) { Ap = A1; la = lda1; kk = k0; }
        else             { Ap = A2; la = lda2; kk = k0 - ksplit; }
        const float4* ga = (const float4*)(Ap + (size_t)arow * la + kk + shalf * 16);
        float4 a0 = ga[0], a1 = ga[1];
        const float4* gb = (const float4*)(Bt + (size_t)brow * ldb + k0 + shalf * 16);
        float4 b0 = gb[0], b1 = gb[1];

        __syncthreads();
        *(float4*)(As + srow * 80 + shalf * 32)      = a0;
        *(float4*)(As + srow * 80 + shalf * 32 + 16) = a1;
        *(float4*)(Bs + srow * 80 + shalf * 32)      = b0;
        *(float4*)(Bs + srow * 80 + shalf * 32 + 16) = b1;
        __syncthreads();

        short8 av[4], bv[4];
        #pragma unroll
        for (int f = 0; f < 4; ++f) {
            av[f] = *(const short8*)(As + (wm * 64 + f * 16 + lm) * 80 + lg * 16);
            bv[f] = *(const short8*)(Bs + (wn * 64 + f * 16 + lm) * 80 + lg * 16);
        }
        #pragma unroll
        for (int i = 0; i < 4; ++i)
            #pragma unroll
            for (int j = 0; j < 4; ++j)
                acc[i][j] = __builtin_amdgcn_mfma_f32_16x16x32_bf16(
                    av[i], bv[j], acc[i][j], 0, 0, 0);
    }

    #pragma unroll
    for (int i = 0; i < 4; ++i) {
        int row0 = bm + wm * 64 + i * 16 + lg * 4;
        #pragma unroll
        for (int j = 0; j < 4; ++j) {
            int col = bn + wn * 64 + j * 16 + lm;
            float bb = bias[col];
            #pragma unroll
            for (int r = 0; r < 4; ++r) {
                int row = row0 + r;
                if (row < M) {
                    float v = acc[i][j][r] + bb;
                    if (RELU) v = fmaxf(v, 0.f);
                    if (OUT == 0) {
                        ((unsigned short*)Cv)[(size_t)row * ldc + col] = f2bf(v);
                    } else {
                        unsigned int pk = __builtin_amdgcn_cvt_pk_fp8_f32(v, v, 0, false);
                        ((unsigned char*)Cv)[(size_t)row * ldc + col] = (unsigned char)pk;
                    }
                }
            }
        }
    }
}

// ---------------------------------------------------------------------------
// CSR build
// ---------------------------------------------------------------------------
__global__ void hist_kernel(const int* __restrict__ dst, int* __restrict__ cnt, int e)
{
    int i = blockIdx.x * 256 + threadIdx.x;
    if (i < e) atomicAdd(&cnt[dst[i]], 1);
}

__global__ __launch_bounds__(256) void scan_part(const int* __restrict__ cnt,
                                                 int* __restrict__ off,
                                                 int* __restrict__ bsum, int n)
{
    int lane = threadIdx.x & 63, wid = threadIdx.x >> 6;
    int i = blockIdx.x * 256 + threadIdx.x;
    int v = (i < n) ? cnt[i] : 0;
    int x = v;
    #pragma unroll
    for (int ofs = 1; ofs < 64; ofs <<= 1) {
        int t = __shfl_up(x, ofs, 64);
        if (lane >= ofs) x += t;
    }
    __shared__ int ws[4];
    if (lane == 63) ws[wid] = x;
    __syncthreads();
    int wo = 0;
    for (int j = 0; j < wid; ++j) wo += ws[j];
    if (i < n) off[i] = wo + x - v;
    if (threadIdx.x == 255) bsum[blockIdx.x] = wo + x;
}

__global__ __launch_bounds__(128) void scan_tops(const int* __restrict__ bsum,
                                                 int* __restrict__ btop, int nb)
{
    __shared__ int buf[128];
    int v = (threadIdx.x < nb) ? bsum[threadIdx.x] : 0;
    buf[threadIdx.x] = v;
    __syncthreads();
    #pragma unroll
    for (int ofs = 1; ofs < 128; ofs <<= 1) {
        int t = (threadIdx.x >= ofs) ? buf[threadIdx.x - ofs] : 0;
        __syncthreads();
        buf[threadIdx.x] += t;
        __syncthreads();
    }
    if (threadIdx.x < nb) btop[threadIdx.x] = buf[threadIdx.x] - v;
}

__global__ __launch_bounds__(256) void scan_add(int* __restrict__ off,
                                                const int* __restrict__ btop,
                                                int* __restrict__ cursor,
                                                int* __restrict__ cnt, int n)
{
    int i = blockIdx.x * 256 + threadIdx.x;
    if (i < n) {
        int o = off[i] + btop[blockIdx.x];
        off[i] = o;
        cursor[i] = o;
        cnt[i] = 0;
    }
    if (blockIdx.x == 0 && threadIdx.x == 0) off[n] = EE;
}

__global__ void fill_kernel(const int* __restrict__ src, const int* __restrict__ dst,
                            const float* __restrict__ sw,
                            int* __restrict__ cursor, int* __restrict__ csr_src,
                            uint2* __restrict__ swp, int e)
{
    int i = blockIdx.x * 256 + threadIdx.x;
    if (i >= e) return;
    int pos = atomicAdd(&cursor[dst[i]], 1);
    csr_src[pos] = src[i];
    uint2 lo, hi;
    lo.x = packbf(sw[i],                   sw[(size_t)EE + i]);
    lo.y = packbf(sw[2 * (size_t)EE + i],  0.f);
    hi.x = packbf(sw[3 * (size_t)EE + i],  sw[4 * (size_t)EE + i]);
    hi.y = packbf(sw[5 * (size_t)EE + i],  0.f);
    swp[(size_t)pos * 2]     = lo;
    swp[(size_t)pos * 2 + 1] = hi;
}

// ---------------------------------------------------------------------------
// Fused 6-conv weighted segment-mean gather, unroll-4 software pipeline.
// ---------------------------------------------------------------------------
__global__ __launch_bounds__(256) void gather6(
    const unsigned char* __restrict__ h8,
    const uint2* __restrict__ swp,
    const int* __restrict__ csr_src,
    const int* __restrict__ off,
    unsigned short* __restrict__ agg)
{
    int wid  = threadIdx.x >> 6;
    int lane = threadIdx.x & 63;
    int node = blockIdx.x * 2 + (wid >> 1);
    int half = wid & 1;
    if (node >= NN) return;
    int s0 = off[node], s1 = off[node + 1];
    float a0 = 0.f, a1 = 0.f, b0 = 0.f, b1 = 0.f, c0 = 0.f, c1 = 0.f;
    const size_t hofs = (size_t)half * 384 + (size_t)lane * 2;

    int e = s0;
    for (; e + 3 < s1; e += 4) {
        int sA = csr_src[e],     sB = csr_src[e + 1];
        int sC = csr_src[e + 2], sD = csr_src[e + 3];
        uint2 wA = swp[(size_t)(e    ) * 2 + half];
        uint2 wB = swp[(size_t)(e + 1) * 2 + half];
        uint2 wC = swp[(size_t)(e + 2) * 2 + half];
        uint2 wD = swp[(size_t)(e + 3) * 2 + half];
        const unsigned short* rA = (const unsigned short*)(h8 + (size_t)sA * 768 + hofs);
        const unsigned short* rB = (const unsigned short*)(h8 + (size_t)sB * 768 + hofs);
        const unsigned short* rC = (const unsigned short*)(h8 + (size_t)sC * 768 + hofs);
        const unsigned short* rD = (const unsigned short*)(h8 + (size_t)sD * 768 + hofs);
        unsigned int pA0 = rA[0], pA1 = rA[64], pA2 = rA[128];
        unsigned int pB0 = rB[0], pB1 = rB[64], pB2 = rB[128];
        unsigned int pC0 = rC[0], pC1 = rC[64], pC2 = rC[128];
        unsigned int pD0 = rD[0], pD1 = rD[64], pD2 = rD[128];

        {
            float w0 = bf2f(wA.x & 0xffffu), w1 = bf2f(wA.x >> 16), w2 = bf2f(wA.y & 0xffffu);
            f32x2 h0 = __builtin_amdgcn_cvt_pk_f32_fp8(pA0, false);
            f32x2 h1 = __builtin_amdgcn_cvt_pk_f32_fp8(pA1, false);
            f32x2 h2 = __builtin_amdgcn_cvt_pk_f32_fp8(pA2, false);
            a0 += w0 * h0.x; a1 += w0 * h0.y;
            b0 += w1 * h1.x; b1 += w1 * h1.y;
            c0 += w2 * h2.x; c1 += w2 * h2.y;
        }
        {
            float w0 = bf2f(wB.x & 0xffffu), w1 = bf2f(wB.x >> 16), w2 = bf2f(wB.y & 0xffffu);
            f32x2 h0 = __builtin_amdgcn_cvt_pk_f32_fp8(pB0, false);
            f32x2 h1 = __builtin_amdgcn_cvt_pk_f32_fp8(pB1, false);
            f32x2 h2 = __builtin_amdgcn_cvt_pk_f32_fp8(pB2, false);
            a0 += w0 * h0.x; a1 += w0 * h0.y;
            b0 += w1 * h1.x; b1 += w1 * h1.y;
            c0 += w2 * h2.x; c1 += w2 * h2.y;
        }
        {
            float w0 = bf2f(wC.x & 0xffffu), w1 = bf2f(wC.x >> 16), w2 = bf2f(wC.y & 0xffffu);
            f32x2 h0 = __builtin_amdgcn_cvt_pk_f32_fp8(pC0, false);
            f32x2 h1 = __builtin_amdgcn_cvt_pk_f32_fp8(pC1, false);
            f32x2 h2 = __builtin_amdgcn_cvt_pk_f32_fp8(pC2, false);
            a0 += w0 * h0.x; a1 += w0 * h0.y;
            b0 += w1 * h1.x; b1 += w1 * h1.y;
            c0 += w2 * h2.x; c1 += w2 * h2.y;
        }
        {
            float w0 = bf2f(wD.x & 0xffffu), w1 = bf2f(wD.x >> 16), w2 = bf2f(wD.y & 0xffffu);
            f32x2 h0 = __builtin_amdgcn_cvt_pk_f32_fp8(pD0, false);
            f32x2 h1 = __builtin_amdgcn_cvt_pk_f32_fp8(pD1, false);
            f32x2 h2 = __builtin_amdgcn_cvt_pk_f32_fp8(pD2, false);
            a0 += w0 * h0.x; a1 += w0 * h0.y;
            b0 += w1 * h1.x; b1 += w1 * h1.y;
            c0 += w2 * h2.x; c1 += w2 * h2.y;
        }
    }
    for (; e < s1; ++e) {
        int src = csr_src[e];
        uint2 wv = swp[(size_t)e * 2 + half];
        float w0 = bf2f(wv.x & 0xffffu);
        float w1 = bf2f(wv.x >> 16);
        float w2 = bf2f(wv.y & 0xffffu);
        const unsigned short* hrow = (const unsigned short*)(h8 + (size_t)src * 768 + hofs);
        unsigned int p0 = hrow[0];
        unsigned int p1 = hrow[64];
        unsigned int p2 = hrow[128];
        f32x2 h0 = __builtin_amdgcn_cvt_pk_f32_fp8(p0, false);
        f32x2 h1 = __builtin_amdgcn_cvt_pk_f32_fp8(p1, false);
        f32x2 h2 = __builtin_amdgcn_cvt_pk_f32_fp8(p2, false);
        a0 += w0 * h0.x; a1 += w0 * h0.y;
        b0 += w1 * h1.x; b1 += w1 * h1.y;
        c0 += w2 * h2.x; c1 += w2 * h2.y;
    }
    float inv = 1.f / fmaxf((float)(s1 - s0), 1.f);
    unsigned int* orow = (unsigned int*)(agg + (size_t)node * 768) + 192 * half + lane;
    orow[0]   = packbf(a0 * inv, a1 * inv);
    orow[64]  = packbf(b0 * inv, b1 * inv);
    orow[128] = packbf(c0 * inv, c1 * inv);
}

// ---------------------------------------------------------------------------
__global__ void cvt_h(const float* __restrict__ Hk, unsigned int* __restrict__ out,
                      int total)
{
    int idx = blockIdx.x * 256 + threadIdx.x;
    if (idx >= total) return;
    float2 v = ((const float2*)Hk)[idx];
    out[idx] = packbf(v.x, v.y);
}

// ---------------------------------------------------------------------------
// Fused 3-step LSTM, gate-interleaved weights. Block = 32 nodes, 4 waves.
// Wave w computes ALL FOUR gates for feature slice d in [32w, 32w+32):
// permuted weight row n' = w*128 + cc, cc = gate*32 + d32, maps to original
// n = gate*128 + w*32 + d32. Gates live entirely in acc registers; bias added
// in fp32; c-state in registers; h round-trips through the 16KB A-LDS only.
// ---------------------------------------------------------------------------
#define SWA32(r, b) ((r) * 512 + ((b) ^ (((r) & 7) << 4)))

__global__ __launch_bounds__(256) void lstm_fused(
    const unsigned short* __restrict__ xs,   // [3][NN][128]
    const unsigned short* __restrict__ Wt,   // [512][256] permuted rows
    const float* __restrict__ bsum,          // [512] permuted
    float* __restrict__ outp)                // [NN][128]
{
    __shared__ __align__(16) unsigned char AL[32 * 512];

    const int tid  = threadIdx.x;
    const int lane = tid & 63;
    const int w    = tid >> 6;
    const int lm   = lane & 15, lg = lane >> 4;
    const int node0 = blockIdx.x * 32;

    float bias[2][4];
    #pragma unroll
    for (int nh = 0; nh < 2; ++nh)
        #pragma unroll
        for (int j = 0; j < 4; ++j)
            bias[nh][j] = bsum[w * 128 + nh * 64 + j * 16 + lm];

    float cst[2][2][4] = {};   // [i][j01][r]

    // zero h half of A-LDS (bytes 256..511 of each row)
    float4 z4 = make_float4(0.f, 0.f, 0.f, 0.f);
    for (int qq = tid; qq < 512; qq += 256) {
        int r = qq >> 4, gi = qq & 15;
        *(float4*)(AL + SWA32(r, 256 + gi * 16)) = z4;
    }

    for (int t = 0; t < KH; ++t) {
        // stage xs_t (bytes 0..255 of each row)
        const unsigned short* xsrc = xs + (size_t)t * NN * 128;
        for (int qq = tid; qq < 512; qq += 256) {
            int r = qq >> 4, gi = qq & 15;
            int gr = node0 + r; if (gr >= NN) gr = NN - 1;
            float4 v = *(const float4*)(xsrc + (size_t)gr * 128 + gi * 8);
            *(float4*)(AL + SWA32(r, gi * 16)) = v;
        }
        __syncthreads();   // xs_t staged + h_t (prev EW) visible

        f32x4 acc[2][2][4] = {};   // [nh][i][j]
        #pragma unroll
        for (int ks = 0; ks < 8; ++ks) {
            short8 av[2];
            #pragma unroll
            for (int i = 0; i < 2; ++i)
                av[i] = *(const short8*)(AL + SWA32(i * 16 + lm, ks * 64 + lg * 16));
            #pragma unroll
            for (int nh = 0; nh < 2; ++nh)
                #pragma unroll
                for (int j = 0; j < 4; ++j) {
                    short8 bv = *(const short8*)(Wt +
                        (size_t)(w * 128 + nh * 64 + j * 16 + lm) * 256 + ks * 32 + lg * 8);
                    #pragma unroll
                    for (int i = 0; i < 2; ++i)
                        acc[nh][i][j] = __builtin_amdgcn_mfma_f32_16x16x32_bf16(
                            av[i], bv, acc[nh][i][j], 0, 0, 0);
                }
        }
        __syncthreads();   // all MFMA reads of h_t done before overwrite

        #pragma unroll
        for (int i = 0; i < 2; ++i)
            #pragma unroll
            for (int j01 = 0; j01 < 2; ++j01)
                #pragma unroll
                for (int r = 0; r < 4; ++r) {
                    float giv = acc[0][i][j01][r]     + bias[0][j01];
                    float gfv = acc[0][i][j01 + 2][r] + bias[0][j01 + 2];
                    float ggv = acc[1][i][j01][r]     + bias[1][j01];
                    float gov = acc[1][i][j01 + 2][r] + bias[1][j01 + 2];
                    float si = 1.f / (1.f + expf(-giv));
                    float sf = 1.f / (1.f + expf(-gfv));
                    float so = 1.f / (1.f + expf(-gov));
                    float cv = sf * cst[i][j01][r] + si * tanhf(ggv);
                    cst[i][j01][r] = cv;
                    float hv = so * tanhf(cv);
                    int row = i * 16 + lg * 4 + r;
                    int d   = w * 32 + j01 * 16 + lm;
                    if (t < KH - 1) {
                        *(unsigned short*)(AL + SWA32(row, 256 + 2 * d)) = f2bf(hv);
                    } else if (node0 + row < NN) {
                        outp[(size_t)(node0 + row) * 128 + d] = fmaxf(hv, 0.f);
                    }
                }
    }
}

// ---------------------------------------------------------------------------
// Weight precompute (once per launch, tiny)
// ---------------------------------------------------------------------------
__global__ void wt_wp(const float* __restrict__ Wp, unsigned short* __restrict__ Wp_t)
{
    int idx = blockIdx.x * 256 + threadIdx.x;
    if (idx >= NC * DIM * DIM) return;
    int k = idx & 127, n = idx >> 7;
    int i = n >> 7, cc = n & 127;
    Wp_t[idx] = f2bf(Wp[(size_t)i * DIM * DIM + (size_t)k * DIM + cc]);
}

__global__ void wt_full(const float* __restrict__ Wcomb, const float* __restrict__ Wroot,
                        const float* __restrict__ Wrel, unsigned short* __restrict__ Wfull_t)
{
    int idx = blockIdx.x * 256 + threadIdx.x;
    if (idx >= 384 * 896) return;
    int m = idx % 896, n = idx / 896;
    float v;
    if (m < 128) {
        v = Wcomb[(size_t)m * 384 + n];
        for (int i = 0; i < NC; ++i) {
            const float* wr = Wroot + (size_t)i * DIM * DIM + (size_t)m * DIM;
            const float* wc = Wcomb + (size_t)(i + 1) * DIM * 384 + n;
            float s = 0.f;
            for (int k = 0; k < DIM; ++k) s += wr[k] * wc[(size_t)k * 384];
            v += s;
        }
    } else {
        int i = (m >> 7) - 1, rr = m & 127;
        const float* wr = Wrel + (size_t)i * DIM * DIM + (size_t)rr * DIM;
        const float* wc = Wcomb + (size_t)(i + 1) * DIM * 384 + n;
        float s = 0.f;
        for (int k = 0; k < DIM; ++k) s += wr[k] * wc[(size_t)k * 384];
        v = s;
    }
    Wfull_t[idx] = f2bf(v);
}

__global__ void wt_pl(const float* __restrict__ Wpl, unsigned short* __restrict__ Wpl_t)
{
    int idx = blockIdx.x * 256 + threadIdx.x;
    if (idx >= 128 * 512) return;
    int k = idx & 511, n = idx >> 9;
    Wpl_t[idx] = f2bf(Wpl[(size_t)k * DIM + n]);
}

// Gate-interleaved LSTM weights: permuted row n' = w*128 + gate*32 + d32
// maps to original row n = gate*128 + w*32 + d32. Same permutation for bias.
__global__ void wt_lstm(const float* __restrict__ Wih, const float* __restrict__ Whh,
                        const float* __restrict__ bih, const float* __restrict__ bhh,
                        unsigned short* __restrict__ Wt, float* __restrict__ bsum)
{
    int idx = blockIdx.x * 256 + threadIdx.x;
    if (idx < 512) {
        int w = idx >> 7, cc = idx & 127, g = cc >> 5, d32 = cc & 31;
        int n = g * 128 + w * 32 + d32;
        bsum[idx] = bih[n] + bhh[n];
    }
    if (idx >= 512 * 256) return;
    int k = idx & 255, np = idx >> 8;
    int w = np >> 7, cc = np & 127, g = cc >> 5, d32 = cc & 31;
    int n = g * 128 + w * 32 + d32;
    Wt[idx] = f2bf(k < 128 ? Wih[(size_t)n * DIM + k]
                           : Whh[(size_t)n * DIM + (k - 128)]);
}

// ---------------------------------------------------------------------------
extern "C" void kernel_launch(void* const* d_in, const int* in_sizes, int n_in,
                              void* d_out, int out_size, void* d_ws, size_t ws_size,
                              hipStream_t stream)
{
    const float* H     = (const float*)d_in[0];
    const int*   EL    = (const int*)  d_in[1];
    const float* SW    = (const float*)d_in[2];
    const float* Wp    = (const float*)d_in[3];
    const float* bp    = (const float*)d_in[4];
    const float* Wrel  = (const float*)d_in[5];
    const float* Wroot = (const float*)d_in[6];
    const float* Wcomb = (const float*)d_in[7];
    const float* bcomb = (const float*)d_in[8];
    const float* Wpl   = (const float*)d_in[9];
    const float* bpl   = (const float*)d_in[10];
    const float* Wih   = (const float*)d_in[11];
    const float* Whh   = (const float*)d_in[12];
    const float* bih   = (const float*)d_in[13];
    const float* bhh   = (const float*)d_in[14];

    char* wp = (char*)d_ws;
    auto alloc = [&](size_t b) {
        char* p = wp; wp += (b + 255) & ~(size_t)255; return p;
    };
    unsigned short* Hbf  = (unsigned short*)alloc((size_t)NN * 128 * 2);
    unsigned char*  h8   = (unsigned char*) alloc((size_t)NN * 768);
    unsigned short* agg  = (unsigned short*)alloc((size_t)NN * 768 * 2);
    unsigned short* proj = (unsigned short*)alloc((size_t)NN * 384 * 2);
    unsigned short* xs   = (unsigned short*)alloc((size_t)KH * NN * 128 * 2);
    int* cnt     = (int*)alloc((size_t)NN * 4);
    int* off     = (int*)alloc((size_t)(NN + 1) * 4);
    int* cursor  = (int*)alloc((size_t)NN * 4);
    int* bsum    = (int*)alloc((size_t)NBLK * 4);
    int* btop    = (int*)alloc((size_t)NBLK * 4);
    int* csr_src = (int*)alloc((size_t)EE * 4);
    uint2* swp   = (uint2*)alloc((size_t)EE * 16);
    unsigned short* Wp_t     = (unsigned short*)alloc((size_t)768 * 128 * 2);
    unsigned short* Wfull_t  = (unsigned short*)alloc((size_t)384 * 896 * 2);
    unsigned short* Wpl_t    = (unsigned short*)alloc((size_t)128 * 512 * 2);
    unsigned short* WihWhh_t = (unsigned short*)alloc((size_t)512 * 256 * 2);
    float* bias_lstm         = (float*)alloc(512 * 4);

    // ---- weight precompute ----
    wt_wp  <<<(NC * DIM * DIM + 255) / 256, 256, 0, stream>>>(Wp, Wp_t);
    wt_full<<<(384 * 896 + 255) / 256,     256, 0, stream>>>(Wcomb, Wroot, Wrel, Wfull_t);
    wt_pl  <<<(128 * 512 + 255) / 256,     256, 0, stream>>>(Wpl, Wpl_t);
    wt_lstm<<<(512 * 256 + 255) / 256,     256, 0, stream>>>(Wih, Whh, bih, bhh,
                                                             WihWhh_t, bias_lstm);

    hipMemsetAsync(cnt, 0, (size_t)NN * 4, stream);

    const int MB = (NN + 127) / 128;   // 235

    for (int k = 0; k < KH; ++k) {
        const float* Hk   = H + (size_t)k * NN * DIM;
        const int*   srcp = EL + (size_t)k * 2 * EE;
        const int*   dstp = srcp + EE;

        hist_kernel<<<(EE + 255) / 256, 256, 0, stream>>>(dstp, cnt, EE);
        scan_part<<<NBLK, 256, 0, stream>>>(cnt, off, bsum, NN);
        scan_tops<<<1, 128, 0, stream>>>(bsum, btop, NBLK);
        scan_add<<<NBLK, 256, 0, stream>>>(off, btop, cursor, cnt, NN);
        fill_kernel<<<(EE + 255) / 256, 256, 0, stream>>>(
            srcp, dstp, SW + (size_t)k * NC * EE, cursor, csr_src, swp, EE);

        cvt_h<<<(NN * 64 + 255) / 256, 256, 0, stream>>>(Hk, (unsigned int*)Hbf, NN * 64);

        // h8 = fp8(relu(Hbf @ Wp_all + bp))   [NN,768]
        mgemm<1, true><<<6 * MB, 256, 0, stream>>>(
            Hbf, 128, (const unsigned short*)nullptr, 0, 128,
            Wp_t, 128, bp, h8, 768, NN, 128, 6);

        gather6<<<NN / 2, 256, 0, stream>>>(h8, swp, csr_src, off, agg);

        // proj = relu([Hbf|agg] @ Wfull + bcomb)   [NN,384]
        mgemm<0, true><<<3 * MB, 256, 0, stream>>>(
            Hbf, 128, agg, 768, 128,
            Wfull_t, 896, bcomb, proj, 384, NN, 896, 3);

        // xs_k = [Hbf|proj] @ Wpl + bpl   [NN,128]
        mgemm<0, false><<<1 * MB, 256, 0, stream>>>(
            Hbf, 128, proj, 384, 128,
            Wpl_t, 512, bpl, xs + (size_t)k * NN * 128, 128, NN, 512, 1);
    }

    // ---- fused LSTM ----
    lstm_fused<<<(NN + 31) / 32, 256, 0, stream>>>(xs, WihWhh_t, bias_lstm,
                                                   (float*)d_out);
}

// Round 6
// 834.944 us; speedup vs baseline: 4.8964x; 1.0274x over previous
//
#include <hip/hip_runtime.h>
#include <math.h>

constexpr int NN  = 30000;
constexpr int DIM = 128;
constexpr int KH  = 3;
constexpr int NC  = 6;
constexpr int EE  = 480000;
constexpr int NBLK = (NN + 255) / 256;   // 118 scan blocks

typedef __attribute__((ext_vector_type(8))) short short8;
typedef __attribute__((ext_vector_type(4))) float f32x4;
typedef __attribute__((ext_vector_type(2))) float f32x2;

__device__ __forceinline__ unsigned short f2bf(float f) {
    union { float f; unsigned int i; } c; c.f = f;
    unsigned int u = c.i;
    return (unsigned short)((u + 0x7fffu + ((u >> 16) & 1u)) >> 16);
}
__device__ __forceinline__ float bf2f(unsigned int u) {
    union { unsigned int i; float f; } c; c.i = u << 16; return c.f;
}
__device__ __forceinline__ unsigned int packbf(float x, float y) {
    return (unsigned int)f2bf(x) | ((unsigned int)f2bf(y) << 16);
}
__device__ __forceinline__ float fsig(float x) {
    return __builtin_amdgcn_rcpf(1.f + __expf(-x));
}
__device__ __forceinline__ float ftanh(float x) {
    return 2.f * fsig(2.f * x) - 1.f;
}

// ---------------------------------------------------------------------------
// bf16 MFMA GEMM: C[M,N] = act( A[M,K] @ B[K,N] + bias ), Bt[N,K] transposed.
// A split at ksplit between A1/A2. OUT: 0 = bf16 C, 1 = fp8(e4m3) C.
// 1D grid, XCD-chunked bijective swizzle for A-panel L2 locality.
// ---------------------------------------------------------------------------
template<int OUT, bool RELU>
__global__ __launch_bounds__(256) void mgemm(
    const unsigned short* __restrict__ A1, int lda1,
    const unsigned short* __restrict__ A2, int lda2, int ksplit,
    const unsigned short* __restrict__ Bt, int ldb,
    const float* __restrict__ bias,
    void* __restrict__ Cv, int ldc,
    int M, int K, int nx)
{
    __shared__ __align__(16) unsigned char smem[2 * 128 * 80];
    unsigned char* As = smem;
    unsigned char* Bs = smem + 128 * 80;

    const int nwg  = gridDim.x;
    const int orig = blockIdx.x;
    const int q = nwg >> 3, r = nwg & 7;
    const int xcd = orig & 7, idx = orig >> 3;
    const int lin = (xcd < r ? xcd * (q + 1) : r * (q + 1) + (xcd - r) * q) + idx;
    const int bx = lin % nx, by = lin / nx;

    const int tid  = threadIdx.x;
    const int lane = tid & 63;
    const int w    = tid >> 6;
    const int wm   = w >> 1, wn = w & 1;
    const int lm   = lane & 15, lg = lane >> 4;
    const int bm   = by * 128;
    const int bn   = bx * 128;

    const int srow  = tid >> 1;
    const int shalf = tid & 1;

    f32x4 acc[4][4] = {};

    int arow = bm + srow; if (arow > M - 1) arow = M - 1;
    const int brow = bn + srow;

    for (int k0 = 0; k0 < K; k0 += 32) {
        const unsigned short* Ap; int la; int kk;
        if (k0 < ksplit) { Ap = A1; la = lda1; kk = k0; }
        else             { Ap = A2; la = lda2; kk = k0 - ksplit; }
        const float4* ga = (const float4*)(Ap + (size_t)arow * la + kk + shalf * 16);
        float4 a0 = ga[0], a1 = ga[1];
        const float4* gb = (const float4*)(Bt + (size_t)brow * ldb + k0 + shalf * 16);
        float4 b0 = gb[0], b1 = gb[1];

        __syncthreads();
        *(float4*)(As + srow * 80 + shalf * 32)      = a0;
        *(float4*)(As + srow * 80 + shalf * 32 + 16) = a1;
        *(float4*)(Bs + srow * 80 + shalf * 32)      = b0;
        *(float4*)(Bs + srow * 80 + shalf * 32 + 16) = b1;
        __syncthreads();

        short8 av[4], bv[4];
        #pragma unroll
        for (int f = 0; f < 4; ++f) {
            av[f] = *(const short8*)(As + (wm * 64 + f * 16 + lm) * 80 + lg * 16);
            bv[f] = *(const short8*)(Bs + (wn * 64 + f * 16 + lm) * 80 + lg * 16);
        }
        #pragma unroll
        for (int i = 0; i < 4; ++i)
            #pragma unroll
            for (int j = 0; j < 4; ++j)
                acc[i][j] = __builtin_amdgcn_mfma_f32_16x16x32_bf16(
                    av[i], bv[j], acc[i][j], 0, 0, 0);
    }

    #pragma unroll
    for (int i = 0; i < 4; ++i) {
        int row0 = bm + wm * 64 + i * 16 + lg * 4;
        #pragma unroll
        for (int j = 0; j < 4; ++j) {
            int col = bn + wn * 64 + j * 16 + lm;
            float bb = bias[col];
            #pragma unroll
            for (int r = 0; r < 4; ++r) {
                int row = row0 + r;
                if (row < M) {
                    float v = acc[i][j][r] + bb;
                    if (RELU) v = fmaxf(v, 0.f);
                    if (OUT == 0) {
                        ((unsigned short*)Cv)[(size_t)row * ldc + col] = f2bf(v);
                    } else {
                        unsigned int pk = __builtin_amdgcn_cvt_pk_fp8_f32(v, v, 0, false);
                        ((unsigned char*)Cv)[(size_t)row * ldc + col] = (unsigned char)pk;
                    }
                }
            }
        }
    }
}

// ---------------------------------------------------------------------------
// CSR build
// ---------------------------------------------------------------------------
__global__ void hist_kernel(const int* __restrict__ dst, int* __restrict__ cnt, int e)
{
    int i = blockIdx.x * 256 + threadIdx.x;
    if (i < e) atomicAdd(&cnt[dst[i]], 1);
}

__global__ __launch_bounds__(256) void scan_part(const int* __restrict__ cnt,
                                                 int* __restrict__ off,
                                                 int* __restrict__ bsum, int n)
{
    int lane = threadIdx.x & 63, wid = threadIdx.x >> 6;
    int i = blockIdx.x * 256 + threadIdx.x;
    int v = (i < n) ? cnt[i] : 0;
    int x = v;
    #pragma unroll
    for (int ofs = 1; ofs < 64; ofs <<= 1) {
        int t = __shfl_up(x, ofs, 64);
        if (lane >= ofs) x += t;
    }
    __shared__ int ws[4];
    if (lane == 63) ws[wid] = x;
    __syncthreads();
    int wo = 0;
    for (int j = 0; j < wid; ++j) wo += ws[j];
    if (i < n) off[i] = wo + x - v;
    if (threadIdx.x == 255) bsum[blockIdx.x] = wo + x;
}

__global__ __launch_bounds__(128) void scan_tops(const int* __restrict__ bsum,
                                                 int* __restrict__ btop, int nb)
{
    __shared__ int buf[128];
    int v = (threadIdx.x < nb) ? bsum[threadIdx.x] : 0;
    buf[threadIdx.x] = v;
    __syncthreads();
    #pragma unroll
    for (int ofs = 1; ofs < 128; ofs <<= 1) {
        int t = (threadIdx.x >= ofs) ? buf[threadIdx.x - ofs] : 0;
        __syncthreads();
        buf[threadIdx.x] += t;
        __syncthreads();
    }
    if (threadIdx.x < nb) btop[threadIdx.x] = buf[threadIdx.x] - v;
}

__global__ __launch_bounds__(256) void scan_add(int* __restrict__ off,
                                                const int* __restrict__ btop,
                                                int* __restrict__ cursor,
                                                int* __restrict__ cnt, int n)
{
    int i = blockIdx.x * 256 + threadIdx.x;
    if (i < n) {
        int o = off[i] + btop[blockIdx.x];
        off[i] = o;
        cursor[i] = o;
        cnt[i] = 0;
    }
    if (blockIdx.x == 0 && threadIdx.x == 0) off[n] = EE;
}

__global__ void fill_kernel(const int* __restrict__ src, const int* __restrict__ dst,
                            const float* __restrict__ sw,
                            int* __restrict__ cursor, int* __restrict__ csr_src,
                            uint2* __restrict__ swp, int e)
{
    int i = blockIdx.x * 256 + threadIdx.x;
    if (i >= e) return;
    int pos = atomicAdd(&cursor[dst[i]], 1);
    csr_src[pos] = src[i];
    uint2 lo, hi;
    lo.x = packbf(sw[i],                   sw[(size_t)EE + i]);
    lo.y = packbf(sw[2 * (size_t)EE + i],  0.f);
    hi.x = packbf(sw[3 * (size_t)EE + i],  sw[4 * (size_t)EE + i]);
    hi.y = packbf(sw[5 * (size_t)EE + i],  0.f);
    swp[(size_t)pos * 2]     = lo;
    swp[(size_t)pos * 2 + 1] = hi;
}

// ---------------------------------------------------------------------------
// Fused 6-conv weighted segment-mean gather, unroll-4 software pipeline.
// ---------------------------------------------------------------------------
__global__ __launch_bounds__(256) void gather6(
    const unsigned char* __restrict__ h8,
    const uint2* __restrict__ swp,
    const int* __restrict__ csr_src,
    const int* __restrict__ off,
    unsigned short* __restrict__ agg)
{
    int wid  = threadIdx.x >> 6;
    int lane = threadIdx.x & 63;
    int node = blockIdx.x * 2 + (wid >> 1);
    int half = wid & 1;
    if (node >= NN) return;
    int s0 = off[node], s1 = off[node + 1];
    float a0 = 0.f, a1 = 0.f, b0 = 0.f, b1 = 0.f, c0 = 0.f, c1 = 0.f;
    const size_t hofs = (size_t)half * 384 + (size_t)lane * 2;

    int e = s0;
    for (; e + 3 < s1; e += 4) {
        int sA = csr_src[e],     sB = csr_src[e + 1];
        int sC = csr_src[e + 2], sD = csr_src[e + 3];
        uint2 wA = swp[(size_t)(e    ) * 2 + half];
        uint2 wB = swp[(size_t)(e + 1) * 2 + half];
        uint2 wC = swp[(size_t)(e + 2) * 2 + half];
        uint2 wD = swp[(size_t)(e + 3) * 2 + half];
        const unsigned short* rA = (const unsigned short*)(h8 + (size_t)sA * 768 + hofs);
        const unsigned short* rB = (const unsigned short*)(h8 + (size_t)sB * 768 + hofs);
        const unsigned short* rC = (const unsigned short*)(h8 + (size_t)sC * 768 + hofs);
        const unsigned short* rD = (const unsigned short*)(h8 + (size_t)sD * 768 + hofs);
        unsigned int pA0 = rA[0], pA1 = rA[64], pA2 = rA[128];
        unsigned int pB0 = rB[0], pB1 = rB[64], pB2 = rB[128];
        unsigned int pC0 = rC[0], pC1 = rC[64], pC2 = rC[128];
        unsigned int pD0 = rD[0], pD1 = rD[64], pD2 = rD[128];

        {
            float w0 = bf2f(wA.x & 0xffffu), w1 = bf2f(wA.x >> 16), w2 = bf2f(wA.y & 0xffffu);
            f32x2 h0 = __builtin_amdgcn_cvt_pk_f32_fp8(pA0, false);
            f32x2 h1 = __builtin_amdgcn_cvt_pk_f32_fp8(pA1, false);
            f32x2 h2 = __builtin_amdgcn_cvt_pk_f32_fp8(pA2, false);
            a0 += w0 * h0.x; a1 += w0 * h0.y;
            b0 += w1 * h1.x; b1 += w1 * h1.y;
            c0 += w2 * h2.x; c1 += w2 * h2.y;
        }
        {
            float w0 = bf2f(wB.x & 0xffffu), w1 = bf2f(wB.x >> 16), w2 = bf2f(wB.y & 0xffffu);
            f32x2 h0 = __builtin_amdgcn_cvt_pk_f32_fp8(pB0, false);
            f32x2 h1 = __builtin_amdgcn_cvt_pk_f32_fp8(pB1, false);
            f32x2 h2 = __builtin_amdgcn_cvt_pk_f32_fp8(pB2, false);
            a0 += w0 * h0.x; a1 += w0 * h0.y;
            b0 += w1 * h1.x; b1 += w1 * h1.y;
            c0 += w2 * h2.x; c1 += w2 * h2.y;
        }
        {
            float w0 = bf2f(wC.x & 0xffffu), w1 = bf2f(wC.x >> 16), w2 = bf2f(wC.y & 0xffffu);
            f32x2 h0 = __builtin_amdgcn_cvt_pk_f32_fp8(pC0, false);
            f32x2 h1 = __builtin_amdgcn_cvt_pk_f32_fp8(pC1, false);
            f32x2 h2 = __builtin_amdgcn_cvt_pk_f32_fp8(pC2, false);
            a0 += w0 * h0.x; a1 += w0 * h0.y;
            b0 += w1 * h1.x; b1 += w1 * h1.y;
            c0 += w2 * h2.x; c1 += w2 * h2.y;
        }
        {
            float w0 = bf2f(wD.x & 0xffffu), w1 = bf2f(wD.x >> 16), w2 = bf2f(wD.y & 0xffffu);
            f32x2 h0 = __builtin_amdgcn_cvt_pk_f32_fp8(pD0, false);
            f32x2 h1 = __builtin_amdgcn_cvt_pk_f32_fp8(pD1, false);
            f32x2 h2 = __builtin_amdgcn_cvt_pk_f32_fp8(pD2, false);
            a0 += w0 * h0.x; a1 += w0 * h0.y;
            b0 += w1 * h1.x; b1 += w1 * h1.y;
            c0 += w2 * h2.x; c1 += w2 * h2.y;
        }
    }
    for (; e < s1; ++e) {
        int src = csr_src[e];
        uint2 wv = swp[(size_t)e * 2 + half];
        float w0 = bf2f(wv.x & 0xffffu);
        float w1 = bf2f(wv.x >> 16);
        float w2 = bf2f(wv.y & 0xffffu);
        const unsigned short* hrow = (const unsigned short*)(h8 + (size_t)src * 768 + hofs);
        unsigned int p0 = hrow[0];
        unsigned int p1 = hrow[64];
        unsigned int p2 = hrow[128];
        f32x2 h0 = __builtin_amdgcn_cvt_pk_f32_fp8(p0, false);
        f32x2 h1 = __builtin_amdgcn_cvt_pk_f32_fp8(p1, false);
        f32x2 h2 = __builtin_amdgcn_cvt_pk_f32_fp8(p2, false);
        a0 += w0 * h0.x; a1 += w0 * h0.y;
        b0 += w1 * h1.x; b1 += w1 * h1.y;
        c0 += w2 * h2.x; c1 += w2 * h2.y;
    }
    float inv = 1.f / fmaxf((float)(s1 - s0), 1.f);
    unsigned int* orow = (unsigned int*)(agg + (size_t)node * 768) + 192 * half + lane;
    orow[0]   = packbf(a0 * inv, a1 * inv);
    orow[64]  = packbf(b0 * inv, b1 * inv);
    orow[128] = packbf(c0 * inv, c1 * inv);
}

// ---------------------------------------------------------------------------
__global__ void cvt_h(const float* __restrict__ Hk, unsigned int* __restrict__ out,
                      int total)
{
    int idx = blockIdx.x * 256 + threadIdx.x;
    if (idx >= total) return;
    float2 v = ((const float2*)Hk)[idx];
    out[idx] = packbf(v.x, v.y);
}

// ---------------------------------------------------------------------------
// Fused 3-step LSTM. Block = 32 nodes, 512 threads (8 waves).
// Wave w computes ALL FOUR gates for feature slice d in [16w, 16w+16):
// permuted weight row n' = w*64 + gate*16 + d16 maps to original
// n = gate*128 + w*16 + d16. Gates/c-state in registers; h round-trips
// through the 16KB A-LDS; fast exp/rcp-based sigmoid/tanh.
// ---------------------------------------------------------------------------
#define SWA32(r, b) ((r) * 512 + ((b) ^ (((r) & 7) << 4)))

__global__ __launch_bounds__(512) void lstm_fused(
    const unsigned short* __restrict__ xs,   // [3][NN][128]
    const unsigned short* __restrict__ Wt,   // [512][256] permuted rows
    const float* __restrict__ bsum,          // [512] permuted
    float* __restrict__ outp)                // [NN][128]
{
    __shared__ __align__(16) unsigned char AL[32 * 512];

    const int tid  = threadIdx.x;
    const int lane = tid & 63;
    const int w    = tid >> 6;              // 0..7
    const int lm   = lane & 15, lg = lane >> 4;
    const int node0 = blockIdx.x * 32;

    float bias[4];
    #pragma unroll
    for (int g = 0; g < 4; ++g)
        bias[g] = bsum[w * 64 + g * 16 + lm];

    float cst[2][4] = {};

    // zero h half of A-LDS (bytes 256..511 of each row)
    float4 z4 = make_float4(0.f, 0.f, 0.f, 0.f);
    for (int qq = tid; qq < 512; qq += 512) {
        int r = qq >> 4, gi = qq & 15;
        *(float4*)(AL + SWA32(r, 256 + gi * 16)) = z4;
    }

    for (int t = 0; t < KH; ++t) {
        // stage xs_t (bytes 0..255 of each row)
        const unsigned short* xsrc = xs + (size_t)t * NN * 128;
        for (int qq = tid; qq < 512; qq += 512) {
            int r = qq >> 4, gi = qq & 15;
            int gr = node0 + r; if (gr >= NN) gr = NN - 1;
            float4 v = *(const float4*)(xsrc + (size_t)gr * 128 + gi * 8);
            *(float4*)(AL + SWA32(r, gi * 16)) = v;
        }
        __syncthreads();   // xs_t staged + h_t (prev EW) visible

        f32x4 acc[2][4] = {};   // [i rowblk][gate]
        #pragma unroll
        for (int ks = 0; ks < 8; ++ks) {
            short8 av[2];
            #pragma unroll
            for (int i = 0; i < 2; ++i)
                av[i] = *(const short8*)(AL + SWA32(i * 16 + lm, ks * 64 + lg * 16));
            #pragma unroll
            for (int g = 0; g < 4; ++g) {
                short8 bv = *(const short8*)(Wt +
                    (size_t)(w * 64 + g * 16 + lm) * 256 + ks * 32 + lg * 8);
                #pragma unroll
                for (int i = 0; i < 2; ++i)
                    acc[i][g] = __builtin_amdgcn_mfma_f32_16x16x32_bf16(
                        av[i], bv, acc[i][g], 0, 0, 0);
            }
        }
        __syncthreads();   // all MFMA reads of h_t done before overwrite

        #pragma unroll
        for (int i = 0; i < 2; ++i)
            #pragma unroll
            for (int r = 0; r < 4; ++r) {
                float giv = acc[i][0][r] + bias[0];
                float gfv = acc[i][1][r] + bias[1];
                float ggv = acc[i][2][r] + bias[2];
                float gov = acc[i][3][r] + bias[3];
                float si = fsig(giv);
                float sf = fsig(gfv);
                float so = fsig(gov);
                float cv = sf * cst[i][r] + si * ftanh(ggv);
                cst[i][r] = cv;
                float hv = so * ftanh(cv);
                int row = i * 16 + lg * 4 + r;
                int d   = w * 16 + lm;
                if (t < KH - 1) {
                    *(unsigned short*)(AL + SWA32(row, 256 + 2 * d)) = f2bf(hv);
                } else if (node0 + row < NN) {
                    outp[(size_t)(node0 + row) * 128 + d] = fmaxf(hv, 0.f);
                }
            }
    }
}

// ---------------------------------------------------------------------------
// Weight precompute (once per launch, tiny)
// ---------------------------------------------------------------------------
__global__ void wt_wp(const float* __restrict__ Wp, unsigned short* __restrict__ Wp_t)
{
    int idx = blockIdx.x * 256 + threadIdx.x;
    if (idx >= NC * DIM * DIM) return;
    int k = idx & 127, n = idx >> 7;
    int i = n >> 7, cc = n & 127;
    Wp_t[idx] = f2bf(Wp[(size_t)i * DIM * DIM + (size_t)k * DIM + cc]);
}

__global__ void wt_full(const float* __restrict__ Wcomb, const float* __restrict__ Wroot,
                        const float* __restrict__ Wrel, unsigned short* __restrict__ Wfull_t)
{
    int idx = blockIdx.x * 256 + threadIdx.x;
    if (idx >= 384 * 896) return;
    int m = idx % 896, n = idx / 896;
    float v;
    if (m < 128) {
        v = Wcomb[(size_t)m * 384 + n];
        for (int i = 0; i < NC; ++i) {
            const float* wr = Wroot + (size_t)i * DIM * DIM + (size_t)m * DIM;
            const float* wc = Wcomb + (size_t)(i + 1) * DIM * 384 + n;
            float s = 0.f;
            for (int k = 0; k < DIM; ++k) s += wr[k] * wc[(size_t)k * 384];
            v += s;
        }
    } else {
        int i = (m >> 7) - 1, rr = m & 127;
        const float* wr = Wrel + (size_t)i * DIM * DIM + (size_t)rr * DIM;
        const float* wc = Wcomb + (size_t)(i + 1) * DIM * 384 + n;
        float s = 0.f;
        for (int k = 0; k < DIM; ++k) s += wr[k] * wc[(size_t)k * 384];
        v = s;
    }
    Wfull_t[idx] = f2bf(v);
}

__global__ void wt_pl(const float* __restrict__ Wpl, unsigned short* __restrict__ Wpl_t)
{
    int idx = blockIdx.x * 256 + threadIdx.x;
    if (idx >= 128 * 512) return;
    int k = idx & 511, n = idx >> 9;
    Wpl_t[idx] = f2bf(Wpl[(size_t)k * DIM + n]);
}

// Gate-interleaved LSTM weights for 8-wave kernel: permuted row
// n' = w*64 + gate*16 + d16 maps to original n = gate*128 + w*16 + d16.
__global__ void wt_lstm(const float* __restrict__ Wih, const float* __restrict__ Whh,
                        const float* __restrict__ bih, const float* __restrict__ bhh,
                        unsigned short* __restrict__ Wt, float* __restrict__ bsum)
{
    int idx = blockIdx.x * 256 + threadIdx.x;
    if (idx < 512) {
        int w = idx >> 6, rem = idx & 63, g = rem >> 4, d16 = rem & 15;
        int n = g * 128 + w * 16 + d16;
        bsum[idx] = bih[n] + bhh[n];
    }
    if (idx >= 512 * 256) return;
    int k = idx & 255, np = idx >> 8;
    int w = np >> 6, rem = np & 63, g = rem >> 4, d16 = rem & 15;
    int n = g * 128 + w * 16 + d16;
    Wt[idx] = f2bf(k < 128 ? Wih[(size_t)n * DIM + k]
                           : Whh[(size_t)n * DIM + (k - 128)]);
}

// ---------------------------------------------------------------------------
extern "C" void kernel_launch(void* const* d_in, const int* in_sizes, int n_in,
                              void* d_out, int out_size, void* d_ws, size_t ws_size,
                              hipStream_t stream)
{
    const float* H     = (const float*)d_in[0];
    const int*   EL    = (const int*)  d_in[1];
    const float* SW    = (const float*)d_in[2];
    const float* Wp    = (const float*)d_in[3];
    const float* bp    = (const float*)d_in[4];
    const float* Wrel  = (const float*)d_in[5];
    const float* Wroot = (const float*)d_in[6];
    const float* Wcomb = (const float*)d_in[7];
    const float* bcomb = (const float*)d_in[8];
    const float* Wpl   = (const float*)d_in[9];
    const float* bpl   = (const float*)d_in[10];
    const float* Wih   = (const float*)d_in[11];
    const float* Whh   = (const float*)d_in[12];
    const float* bih   = (const float*)d_in[13];
    const float* bhh   = (const float*)d_in[14];

    char* wp = (char*)d_ws;
    auto alloc = [&](size_t b) {
        char* p = wp; wp += (b + 255) & ~(size_t)255; return p;
    };
    unsigned short* Hbf  = (unsigned short*)alloc((size_t)NN * 128 * 2);
    unsigned char*  h8   = (unsigned char*) alloc((size_t)NN * 768);
    unsigned short* agg  = (unsigned short*)alloc((size_t)NN * 768 * 2);
    unsigned short* proj = (unsigned short*)alloc((size_t)NN * 384 * 2);
    unsigned short* xs   = (unsigned short*)alloc((size_t)KH * NN * 128 * 2);
    int* cnt     = (int*)alloc((size_t)NN * 4);
    int* off     = (int*)alloc((size_t)(NN + 1) * 4);
    int* cursor  = (int*)alloc((size_t)NN * 4);
    int* bsum    = (int*)alloc((size_t)NBLK * 4);
    int* btop    = (int*)alloc((size_t)NBLK * 4);
    int* csr_src = (int*)alloc((size_t)EE * 4);
    uint2* swp   = (uint2*)alloc((size_t)EE * 16);
    unsigned short* Wp_t     = (unsigned short*)alloc((size_t)768 * 128 * 2);
    unsigned short* Wfull_t  = (unsigned short*)alloc((size_t)384 * 896 * 2);
    unsigned short* Wpl_t    = (unsigned short*)alloc((size_t)128 * 512 * 2);
    unsigned short* WihWhh_t = (unsigned short*)alloc((size_t)512 * 256 * 2);
    float* bias_lstm         = (float*)alloc(512 * 4);

    // ---- weight precompute ----
    wt_wp  <<<(NC * DIM * DIM + 255) / 256, 256, 0, stream>>>(Wp, Wp_t);
    wt_full<<<(384 * 896 + 255) / 256,     256, 0, stream>>>(Wcomb, Wroot, Wrel, Wfull_t);
    wt_pl  <<<(128 * 512 + 255) / 256,     256, 0, stream>>>(Wpl, Wpl_t);
    wt_lstm<<<(512 * 256 + 255) / 256,     256, 0, stream>>>(Wih, Whh, bih, bhh,
                                                             WihWhh_t, bias_lstm);

    hipMemsetAsync(cnt, 0, (size_t)NN * 4, stream);

    const int MB = (NN + 127) / 128;   // 235

    for (int k = 0; k < KH; ++k) {
        const float* Hk   = H + (size_t)k * NN * DIM;
        const int*   srcp = EL + (size_t)k * 2 * EE;
        const int*   dstp = srcp + EE;

        hist_kernel<<<(EE + 255) / 256, 256, 0, stream>>>(dstp, cnt, EE);
        scan_part<<<NBLK, 256, 0, stream>>>(cnt, off, bsum, NN);
        scan_tops<<<1, 128, 0, stream>>>(bsum, btop, NBLK);
        scan_add<<<NBLK, 256, 0, stream>>>(off, btop, cursor, cnt, NN);
        fill_kernel<<<(EE + 255) / 256, 256, 0, stream>>>(
            srcp, dstp, SW + (size_t)k * NC * EE, cursor, csr_src, swp, EE);

        cvt_h<<<(NN * 64 + 255) / 256, 256, 0, stream>>>(Hk, (unsigned int*)Hbf, NN * 64);

        // h8 = fp8(relu(Hbf @ Wp_all + bp))   [NN,768]
        mgemm<1, true><<<6 * MB, 256, 0, stream>>>(
            Hbf, 128, (const unsigned short*)nullptr, 0, 128,
            Wp_t, 128, bp, h8, 768, NN, 128, 6);

        gather6<<<NN / 2, 256, 0, stream>>>(h8, swp, csr_src, off, agg);

        // proj = relu([Hbf|agg] @ Wfull + bcomb)   [NN,384]
        mgemm<0, true><<<3 * MB, 256, 0, stream>>>(
            Hbf, 128, agg, 768, 128,
            Wfull_t, 896, bcomb, proj, 384, NN, 896, 3);

        // xs_k = [Hbf|proj] @ Wpl + bpl   [NN,128]
        mgemm<0, false><<<1 * MB, 256, 0, stream>>>(
            Hbf, 128, proj, 384, 128,
            Wpl_t, 512, bpl, xs + (size_t)k * NN * 128, 128, NN, 512, 1);
    }

    // ---- fused LSTM ----
    lstm_fused<<<(NN + 31) / 32, 512, 0, stream>>>(xs, WihWhh_t, bias_lstm,
                                                   (float*)d_out);
}

// Round 7
// 787.598 us; speedup vs baseline: 5.1908x; 1.0601x over previous
//
#include <hip/hip_runtime.h>
#include <math.h>

constexpr int NN  = 30000;
constexpr int DIM = 128;
constexpr int KH  = 3;
constexpr int NC  = 6;
constexpr int EE  = 480000;
constexpr int NBLK = (NN + 255) / 256;   // 118 scan blocks

typedef __attribute__((ext_vector_type(8))) short short8;
typedef __attribute__((ext_vector_type(4))) float f32x4;
typedef __attribute__((ext_vector_type(2))) float f32x2;

__device__ __forceinline__ unsigned short f2bf(float f) {
    union { float f; unsigned int i; } c; c.f = f;
    unsigned int u = c.i;
    return (unsigned short)((u + 0x7fffu + ((u >> 16) & 1u)) >> 16);
}
__device__ __forceinline__ float bf2f(unsigned int u) {
    union { unsigned int i; float f; } c; c.i = u << 16; return c.f;
}
__device__ __forceinline__ unsigned int packbf(float x, float y) {
    return (unsigned int)f2bf(x) | ((unsigned int)f2bf(y) << 16);
}
__device__ __forceinline__ float fsig(float x) {
    return __builtin_amdgcn_rcpf(1.f + __expf(-x));
}
__device__ __forceinline__ float ftanh(float x) {
    return 2.f * fsig(2.f * x) - 1.f;
}

// ---------------------------------------------------------------------------
// bf16 MFMA GEMM: C[M,N] = act( A[M,K] @ B[K,N] + bias ), Bt[N,K] transposed.
// A split at ksplit between A1/A2. OUT: 0 = bf16 C, 1 = fp8(e4m3) C.
// 1D grid, XCD-chunked bijective swizzle for A-panel L2 locality.
// ---------------------------------------------------------------------------
template<int OUT, bool RELU>
__global__ __launch_bounds__(256) void mgemm(
    const unsigned short* __restrict__ A1, int lda1,
    const unsigned short* __restrict__ A2, int lda2, int ksplit,
    const unsigned short* __restrict__ Bt, int ldb,
    const float* __restrict__ bias,
    void* __restrict__ Cv, int ldc,
    int M, int K, int nx)
{
    __shared__ __align__(16) unsigned char smem[2 * 128 * 80];
    unsigned char* As = smem;
    unsigned char* Bs = smem + 128 * 80;

    const int nwg  = gridDim.x;
    const int orig = blockIdx.x;
    const int q = nwg >> 3, r = nwg & 7;
    const int xcd = orig & 7, idx = orig >> 3;
    const int lin = (xcd < r ? xcd * (q + 1) : r * (q + 1) + (xcd - r) * q) + idx;
    const int bx = lin % nx, by = lin / nx;

    const int tid  = threadIdx.x;
    const int lane = tid & 63;
    const int w    = tid >> 6;
    const int wm   = w >> 1, wn = w & 1;
    const int lm   = lane & 15, lg = lane >> 4;
    const int bm   = by * 128;
    const int bn   = bx * 128;

    const int srow  = tid >> 1;
    const int shalf = tid & 1;

    f32x4 acc[4][4] = {};

    int arow = bm + srow; if (arow > M - 1) arow = M - 1;
    const int brow = bn + srow;

    for (int k0 = 0; k0 < K; k0 += 32) {
        const unsigned short* Ap; int la; int kk;
        if (k0 < ksplit) { Ap = A1; la = lda1; kk = k0; }
        else             { Ap = A2; la = lda2; kk = k0 - ksplit; }
        const float4* ga = (const float4*)(Ap + (size_t)arow * la + kk + shalf * 16);
        float4 a0 = ga[0], a1 = ga[1];
        const float4* gb = (const float4*)(Bt + (size_t)brow * ldb + k0 + shalf * 16);
        float4 b0 = gb[0], b1 = gb[1];

        __syncthreads();
        *(float4*)(As + srow * 80 + shalf * 32)      = a0;
        *(float4*)(As + srow * 80 + shalf * 32 + 16) = a1;
        *(float4*)(Bs + srow * 80 + shalf * 32)      = b0;
        *(float4*)(Bs + srow * 80 + shalf * 32 + 16) = b1;
        __syncthreads();

        short8 av[4], bv[4];
        #pragma unroll
        for (int f = 0; f < 4; ++f) {
            av[f] = *(const short8*)(As + (wm * 64 + f * 16 + lm) * 80 + lg * 16);
            bv[f] = *(const short8*)(Bs + (wn * 64 + f * 16 + lm) * 80 + lg * 16);
        }
        #pragma unroll
        for (int i = 0; i < 4; ++i)
            #pragma unroll
            for (int j = 0; j < 4; ++j)
                acc[i][j] = __builtin_amdgcn_mfma_f32_16x16x32_bf16(
                    av[i], bv[j], acc[i][j], 0, 0, 0);
    }

    #pragma unroll
    for (int i = 0; i < 4; ++i) {
        int row0 = bm + wm * 64 + i * 16 + lg * 4;
        #pragma unroll
        for (int j = 0; j < 4; ++j) {
            int col = bn + wn * 64 + j * 16 + lm;
            float bb = bias[col];
            #pragma unroll
            for (int r = 0; r < 4; ++r) {
                int row = row0 + r;
                if (row < M) {
                    float v = acc[i][j][r] + bb;
                    if (RELU) v = fmaxf(v, 0.f);
                    if (OUT == 0) {
                        ((unsigned short*)Cv)[(size_t)row * ldc + col] = f2bf(v);
                    } else {
                        unsigned int pk = __builtin_amdgcn_cvt_pk_fp8_f32(v, v, 0, false);
                        ((unsigned char*)Cv)[(size_t)row * ldc + col] = (unsigned char)pk;
                    }
                }
            }
        }
    }
}

// ---------------------------------------------------------------------------
// CSR build
// ---------------------------------------------------------------------------
__global__ void hist_kernel(const int* __restrict__ dst, int* __restrict__ cnt, int e)
{
    int i = blockIdx.x * 256 + threadIdx.x;
    if (i < e) atomicAdd(&cnt[dst[i]], 1);
}

__global__ __launch_bounds__(256) void scan_part(const int* __restrict__ cnt,
                                                 int* __restrict__ off,
                                                 int* __restrict__ bsum, int n)
{
    int lane = threadIdx.x & 63, wid = threadIdx.x >> 6;
    int i = blockIdx.x * 256 + threadIdx.x;
    int v = (i < n) ? cnt[i] : 0;
    int x = v;
    #pragma unroll
    for (int ofs = 1; ofs < 64; ofs <<= 1) {
        int t = __shfl_up(x, ofs, 64);
        if (lane >= ofs) x += t;
    }
    __shared__ int ws[4];
    if (lane == 63) ws[wid] = x;
    __syncthreads();
    int wo = 0;
    for (int j = 0; j < wid; ++j) wo += ws[j];
    if (i < n) off[i] = wo + x - v;
    if (threadIdx.x == 255) bsum[blockIdx.x] = wo + x;
}

__global__ __launch_bounds__(128) void scan_tops(const int* __restrict__ bsum,
                                                 int* __restrict__ btop, int nb)
{
    __shared__ int buf[128];
    int v = (threadIdx.x < nb) ? bsum[threadIdx.x] : 0;
    buf[threadIdx.x] = v;
    __syncthreads();
    #pragma unroll
    for (int ofs = 1; ofs < 128; ofs <<= 1) {
        int t = (threadIdx.x >= ofs) ? buf[threadIdx.x - ofs] : 0;
        __syncthreads();
        buf[threadIdx.x] += t;
        __syncthreads();
    }
    if (threadIdx.x < nb) btop[threadIdx.x] = buf[threadIdx.x] - v;
}

__global__ __launch_bounds__(256) void scan_add(int* __restrict__ off,
                                                const int* __restrict__ btop,
                                                int* __restrict__ cursor,
                                                int* __restrict__ cnt, int n)
{
    int i = blockIdx.x * 256 + threadIdx.x;
    if (i < n) {
        int o = off[i] + btop[blockIdx.x];
        off[i] = o;
        cursor[i] = o;
        cnt[i] = 0;
    }
    if (blockIdx.x == 0 && threadIdx.x == 0) off[n] = EE;
}

__global__ void fill_kernel(const int* __restrict__ src, const int* __restrict__ dst,
                            const float* __restrict__ sw,
                            int* __restrict__ cursor, int* __restrict__ csr_src,
                            uint2* __restrict__ swp, int e)
{
    int i = blockIdx.x * 256 + threadIdx.x;
    if (i >= e) return;
    int pos = atomicAdd(&cursor[dst[i]], 1);
    csr_src[pos] = src[i];
    uint2 lo, hi;
    lo.x = packbf(sw[i],                   sw[(size_t)EE + i]);
    lo.y = packbf(sw[2 * (size_t)EE + i],  0.f);
    hi.x = packbf(sw[3 * (size_t)EE + i],  sw[4 * (size_t)EE + i]);
    hi.y = packbf(sw[5 * (size_t)EE + i],  0.f);
    swp[(size_t)pos * 2]     = lo;
    swp[(size_t)pos * 2 + 1] = hi;
}

// ---------------------------------------------------------------------------
// Fused 6-conv weighted segment-mean gather, unroll-4 software pipeline.
// ---------------------------------------------------------------------------
__global__ __launch_bounds__(256) void gather6(
    const unsigned char* __restrict__ h8,
    const uint2* __restrict__ swp,
    const int* __restrict__ csr_src,
    const int* __restrict__ off,
    unsigned short* __restrict__ agg)
{
    int wid  = threadIdx.x >> 6;
    int lane = threadIdx.x & 63;
    int node = blockIdx.x * 2 + (wid >> 1);
    int half = wid & 1;
    if (node >= NN) return;
    int s0 = off[node], s1 = off[node + 1];
    float a0 = 0.f, a1 = 0.f, b0 = 0.f, b1 = 0.f, c0 = 0.f, c1 = 0.f;
    const size_t hofs = (size_t)half * 384 + (size_t)lane * 2;

    int e = s0;
    for (; e + 3 < s1; e += 4) {
        int sA = csr_src[e],     sB = csr_src[e + 1];
        int sC = csr_src[e + 2], sD = csr_src[e + 3];
        uint2 wA = swp[(size_t)(e    ) * 2 + half];
        uint2 wB = swp[(size_t)(e + 1) * 2 + half];
        uint2 wC = swp[(size_t)(e + 2) * 2 + half];
        uint2 wD = swp[(size_t)(e + 3) * 2 + half];
        const unsigned short* rA = (const unsigned short*)(h8 + (size_t)sA * 768 + hofs);
        const unsigned short* rB = (const unsigned short*)(h8 + (size_t)sB * 768 + hofs);
        const unsigned short* rC = (const unsigned short*)(h8 + (size_t)sC * 768 + hofs);
        const unsigned short* rD = (const unsigned short*)(h8 + (size_t)sD * 768 + hofs);
        unsigned int pA0 = rA[0], pA1 = rA[64], pA2 = rA[128];
        unsigned int pB0 = rB[0], pB1 = rB[64], pB2 = rB[128];
        unsigned int pC0 = rC[0], pC1 = rC[64], pC2 = rC[128];
        unsigned int pD0 = rD[0], pD1 = rD[64], pD2 = rD[128];

        {
            float w0 = bf2f(wA.x & 0xffffu), w1 = bf2f(wA.x >> 16), w2 = bf2f(wA.y & 0xffffu);
            f32x2 h0 = __builtin_amdgcn_cvt_pk_f32_fp8(pA0, false);
            f32x2 h1 = __builtin_amdgcn_cvt_pk_f32_fp8(pA1, false);
            f32x2 h2 = __builtin_amdgcn_cvt_pk_f32_fp8(pA2, false);
            a0 += w0 * h0.x; a1 += w0 * h0.y;
            b0 += w1 * h1.x; b1 += w1 * h1.y;
            c0 += w2 * h2.x; c1 += w2 * h2.y;
        }
        {
            float w0 = bf2f(wB.x & 0xffffu), w1 = bf2f(wB.x >> 16), w2 = bf2f(wB.y & 0xffffu);
            f32x2 h0 = __builtin_amdgcn_cvt_pk_f32_fp8(pB0, false);
            f32x2 h1 = __builtin_amdgcn_cvt_pk_f32_fp8(pB1, false);
            f32x2 h2 = __builtin_amdgcn_cvt_pk_f32_fp8(pB2, false);
            a0 += w0 * h0.x; a1 += w0 * h0.y;
            b0 += w1 * h1.x; b1 += w1 * h1.y;
            c0 += w2 * h2.x; c1 += w2 * h2.y;
        }
        {
            float w0 = bf2f(wC.x & 0xffffu), w1 = bf2f(wC.x >> 16), w2 = bf2f(wC.y & 0xffffu);
            f32x2 h0 = __builtin_amdgcn_cvt_pk_f32_fp8(pC0, false);
            f32x2 h1 = __builtin_amdgcn_cvt_pk_f32_fp8(pC1, false);
            f32x2 h2 = __builtin_amdgcn_cvt_pk_f32_fp8(pC2, false);
            a0 += w0 * h0.x; a1 += w0 * h0.y;
            b0 += w1 * h1.x; b1 += w1 * h1.y;
            c0 += w2 * h2.x; c1 += w2 * h2.y;
        }
        {
            float w0 = bf2f(wD.x & 0xffffu), w1 = bf2f(wD.x >> 16), w2 = bf2f(wD.y & 0xffffu);
            f32x2 h0 = __builtin_amdgcn_cvt_pk_f32_fp8(pD0, false);
            f32x2 h1 = __builtin_amdgcn_cvt_pk_f32_fp8(pD1, false);
            f32x2 h2 = __builtin_amdgcn_cvt_pk_f32_fp8(pD2, false);
            a0 += w0 * h0.x; a1 += w0 * h0.y;
            b0 += w1 * h1.x; b1 += w1 * h1.y;
            c0 += w2 * h2.x; c1 += w2 * h2.y;
        }
    }
    for (; e < s1; ++e) {
        int src = csr_src[e];
        uint2 wv = swp[(size_t)e * 2 + half];
        float w0 = bf2f(wv.x & 0xffffu);
        float w1 = bf2f(wv.x >> 16);
        float w2 = bf2f(wv.y & 0xffffu);
        const unsigned short* hrow = (const unsigned short*)(h8 + (size_t)src * 768 + hofs);
        unsigned int p0 = hrow[0];
        unsigned int p1 = hrow[64];
        unsigned int p2 = hrow[128];
        f32x2 h0 = __builtin_amdgcn_cvt_pk_f32_fp8(p0, false);
        f32x2 h1 = __builtin_amdgcn_cvt_pk_f32_fp8(p1, false);
        f32x2 h2 = __builtin_amdgcn_cvt_pk_f32_fp8(p2, false);
        a0 += w0 * h0.x; a1 += w0 * h0.y;
        b0 += w1 * h1.x; b1 += w1 * h1.y;
        c0 += w2 * h2.x; c1 += w2 * h2.y;
    }
    float inv = 1.f / fmaxf((float)(s1 - s0), 1.f);
    unsigned int* orow = (unsigned int*)(agg + (size_t)node * 768) + 192 * half + lane;
    orow[0]   = packbf(a0 * inv, a1 * inv);
    orow[64]  = packbf(b0 * inv, b1 * inv);
    orow[128] = packbf(c0 * inv, c1 * inv);
}

// ---------------------------------------------------------------------------
__global__ void cvt_h(const float* __restrict__ Hk, unsigned int* __restrict__ out,
                      int total)
{
    int idx = blockIdx.x * 256 + threadIdx.x;
    if (idx >= total) return;
    float2 v = ((const float2*)Hk)[idx];
    out[idx] = packbf(v.x, v.y);
}

// ---------------------------------------------------------------------------
// Fused 3-step LSTM. Block = 32 nodes, 512 threads (8 waves).
// Wave w computes ALL FOUR gates for feature slice d in [16w, 16w+16).
// Weight fragments hoisted into registers ONCE (invariant across t):
// 32 x short8 = 128 VGPR; the t-loop is pure LDS-read + MFMA + register EW.
// ---------------------------------------------------------------------------
#define SWA32(r, b) ((r) * 512 + ((b) ^ (((r) & 7) << 4)))

__global__ __launch_bounds__(512) void lstm_fused(
    const unsigned short* __restrict__ xs,   // [3][NN][128]
    const unsigned short* __restrict__ Wt,   // [512][256] permuted rows
    const float* __restrict__ bsum,          // [512] permuted
    float* __restrict__ outp)                // [NN][128]
{
    __shared__ __align__(16) unsigned char AL[32 * 512];

    const int tid  = threadIdx.x;
    const int lane = tid & 63;
    const int w    = tid >> 6;              // 0..7
    const int lm   = lane & 15, lg = lane >> 4;
    const int node0 = blockIdx.x * 32;

    float bias[4];
    #pragma unroll
    for (int g = 0; g < 4; ++g)
        bias[g] = bsum[w * 64 + g * 16 + lm];

    // hoist weight fragments: invariant across the 3 timesteps
    short8 bw[8][4];
    #pragma unroll
    for (int ks = 0; ks < 8; ++ks)
        #pragma unroll
        for (int g = 0; g < 4; ++g)
            bw[ks][g] = *(const short8*)(Wt +
                (size_t)(w * 64 + g * 16 + lm) * 256 + ks * 32 + lg * 8);

    float cst[2][4] = {};

    // zero h half of A-LDS (bytes 256..511 of each row)
    float4 z4 = make_float4(0.f, 0.f, 0.f, 0.f);
    {
        int r = tid >> 4, gi = tid & 15;
        *(float4*)(AL + SWA32(r, 256 + gi * 16)) = z4;
    }

    for (int t = 0; t < KH; ++t) {
        // stage xs_t (bytes 0..255 of each row)
        const unsigned short* xsrc = xs + (size_t)t * NN * 128;
        {
            int r = tid >> 4, gi = tid & 15;
            int gr = node0 + r; if (gr >= NN) gr = NN - 1;
            float4 v = *(const float4*)(xsrc + (size_t)gr * 128 + gi * 8);
            *(float4*)(AL + SWA32(r, gi * 16)) = v;
        }
        __syncthreads();   // xs_t staged + h_t (prev EW) visible

        f32x4 acc[2][4] = {};   // [i rowblk][gate]
        #pragma unroll
        for (int ks = 0; ks < 8; ++ks) {
            short8 av[2];
            #pragma unroll
            for (int i = 0; i < 2; ++i)
                av[i] = *(const short8*)(AL + SWA32(i * 16 + lm, ks * 64 + lg * 16));
            #pragma unroll
            for (int g = 0; g < 4; ++g)
                #pragma unroll
                for (int i = 0; i < 2; ++i)
                    acc[i][g] = __builtin_amdgcn_mfma_f32_16x16x32_bf16(
                        av[i], bw[ks][g], acc[i][g], 0, 0, 0);
        }
        __syncthreads();   // all MFMA reads of h_t done before overwrite

        #pragma unroll
        for (int i = 0; i < 2; ++i)
            #pragma unroll
            for (int r = 0; r < 4; ++r) {
                float giv = acc[i][0][r] + bias[0];
                float gfv = acc[i][1][r] + bias[1];
                float ggv = acc[i][2][r] + bias[2];
                float gov = acc[i][3][r] + bias[3];
                float si = fsig(giv);
                float sf = fsig(gfv);
                float so = fsig(gov);
                float cv = sf * cst[i][r] + si * ftanh(ggv);
                cst[i][r] = cv;
                float hv = so * ftanh(cv);
                int row = i * 16 + lg * 4 + r;
                int d   = w * 16 + lm;
                if (t < KH - 1) {
                    *(unsigned short*)(AL + SWA32(row, 256 + 2 * d)) = f2bf(hv);
                } else if (node0 + row < NN) {
                    outp[(size_t)(node0 + row) * 128 + d] = fmaxf(hv, 0.f);
                }
            }
    }
}

// ---------------------------------------------------------------------------
// Weight precompute (once per launch, tiny)
// ---------------------------------------------------------------------------
__global__ void wt_wp(const float* __restrict__ Wp, unsigned short* __restrict__ Wp_t)
{
    int idx = blockIdx.x * 256 + threadIdx.x;
    if (idx >= NC * DIM * DIM) return;
    int k = idx & 127, n = idx >> 7;
    int i = n >> 7, cc = n & 127;
    Wp_t[idx] = f2bf(Wp[(size_t)i * DIM * DIM + (size_t)k * DIM + cc]);
}

__global__ void wt_full(const float* __restrict__ Wcomb, const float* __restrict__ Wroot,
                        const float* __restrict__ Wrel, unsigned short* __restrict__ Wfull_t)
{
    int idx = blockIdx.x * 256 + threadIdx.x;
    if (idx >= 384 * 896) return;
    int m = idx % 896, n = idx / 896;
    float v;
    if (m < 128) {
        v = Wcomb[(size_t)m * 384 + n];
        for (int i = 0; i < NC; ++i) {
            const float* wr = Wroot + (size_t)i * DIM * DIM + (size_t)m * DIM;
            const float* wc = Wcomb + (size_t)(i + 1) * DIM * 384 + n;
            float s = 0.f;
            for (int k = 0; k < DIM; ++k) s += wr[k] * wc[(size_t)k * 384];
            v += s;
        }
    } else {
        int i = (m >> 7) - 1, rr = m & 127;
        const float* wr = Wrel + (size_t)i * DIM * DIM + (size_t)rr * DIM;
        const float* wc = Wcomb + (size_t)(i + 1) * DIM * 384 + n;
        float s = 0.f;
        for (int k = 0; k < DIM; ++k) s += wr[k] * wc[(size_t)k * 384];
        v = s;
    }
    Wfull_t[idx] = f2bf(v);
}

__global__ void wt_pl(const float* __restrict__ Wpl, unsigned short* __restrict__ Wpl_t)
{
    int idx = blockIdx.x * 256 + threadIdx.x;
    if (idx >= 128 * 512) return;
    int k = idx & 511, n = idx >> 9;
    Wpl_t[idx] = f2bf(Wpl[(size_t)k * DIM + n]);
}

// Gate-interleaved LSTM weights for 8-wave kernel: permuted row
// n' = w*64 + gate*16 + d16 maps to original n = gate*128 + w*16 + d16.
__global__ void wt_lstm(const float* __restrict__ Wih, const float* __restrict__ Whh,
                        const float* __restrict__ bih, const float* __restrict__ bhh,
                        unsigned short* __restrict__ Wt, float* __restrict__ bsum)
{
    int idx = blockIdx.x * 256 + threadIdx.x;
    if (idx < 512) {
        int w = idx >> 6, rem = idx & 63, g = rem >> 4, d16 = rem & 15;
        int n = g * 128 + w * 16 + d16;
        bsum[idx] = bih[n] + bhh[n];
    }
    if (idx >= 512 * 256) return;
    int k = idx & 255, np = idx >> 8;
    int w = np >> 6, rem = np & 63, g = rem >> 4, d16 = rem & 15;
    int n = g * 128 + w * 16 + d16;
    Wt[idx] = f2bf(k < 128 ? Wih[(size_t)n * DIM + k]
                           : Whh[(size_t)n * DIM + (k - 128)]);
}

// ---------------------------------------------------------------------------
extern "C" void kernel_launch(void* const* d_in, const int* in_sizes, int n_in,
                              void* d_out, int out_size, void* d_ws, size_t ws_size,
                              hipStream_t stream)
{
    const float* H     = (const float*)d_in[0];
    const int*   EL    = (const int*)  d_in[1];
    const float* SW    = (const float*)d_in[2];
    const float* Wp    = (const float*)d_in[3];
    const float* bp    = (const float*)d_in[4];
    const float* Wrel  = (const float*)d_in[5];
    const float* Wroot = (const float*)d_in[6];
    const float* Wcomb = (const float*)d_in[7];
    const float* bcomb = (const float*)d_in[8];
    const float* Wpl   = (const float*)d_in[9];
    const float* bpl   = (const float*)d_in[10];
    const float* Wih   = (const float*)d_in[11];
    const float* Whh   = (const float*)d_in[12];
    const float* bih   = (const float*)d_in[13];
    const float* bhh   = (const float*)d_in[14];

    char* wp = (char*)d_ws;
    auto alloc = [&](size_t b) {
        char* p = wp; wp += (b + 255) & ~(size_t)255; return p;
    };
    unsigned short* Hbf  = (unsigned short*)alloc((size_t)NN * 128 * 2);
    unsigned char*  h8   = (unsigned char*) alloc((size_t)NN * 768);
    unsigned short* agg  = (unsigned short*)alloc((size_t)NN * 768 * 2);
    unsigned short* proj = (unsigned short*)alloc((size_t)NN * 384 * 2);
    unsigned short* xs   = (unsigned short*)alloc((size_t)KH * NN * 128 * 2);
    int* cnt     = (int*)alloc((size_t)NN * 4);
    int* off     = (int*)alloc((size_t)(NN + 1) * 4);
    int* cursor  = (int*)alloc((size_t)NN * 4);
    int* bsum    = (int*)alloc((size_t)NBLK * 4);
    int* btop    = (int*)alloc((size_t)NBLK * 4);
    int* csr_src = (int*)alloc((size_t)EE * 4);
    uint2* swp   = (uint2*)alloc((size_t)EE * 16);
    unsigned short* Wp_t     = (unsigned short*)alloc((size_t)768 * 128 * 2);
    unsigned short* Wfull_t  = (unsigned short*)alloc((size_t)384 * 896 * 2);
    unsigned short* Wpl_t    = (unsigned short*)alloc((size_t)128 * 512 * 2);
    unsigned short* WihWhh_t = (unsigned short*)alloc((size_t)512 * 256 * 2);
    float* bias_lstm         = (float*)alloc(512 * 4);

    // ---- weight precompute ----
    wt_wp  <<<(NC * DIM * DIM + 255) / 256, 256, 0, stream>>>(Wp, Wp_t);
    wt_full<<<(384 * 896 + 255) / 256,     256, 0, stream>>>(Wcomb, Wroot, Wrel, Wfull_t);
    wt_pl  <<<(128 * 512 + 255) / 256,     256, 0, stream>>>(Wpl, Wpl_t);
    wt_lstm<<<(512 * 256 + 255) / 256,     256, 0, stream>>>(Wih, Whh, bih, bhh,
                                                             WihWhh_t, bias_lstm);

    hipMemsetAsync(cnt, 0, (size_t)NN * 4, stream);

    const int MB = (NN + 127) / 128;   // 235

    for (int k = 0; k < KH; ++k) {
        const float* Hk   = H + (size_t)k * NN * DIM;
        const int*   srcp = EL + (size_t)k * 2 * EE;
        const int*   dstp = srcp + EE;

        hist_kernel<<<(EE + 255) / 256, 256, 0, stream>>>(dstp, cnt, EE);
        scan_part<<<NBLK, 256, 0, stream>>>(cnt, off, bsum, NN);
        scan_tops<<<1, 128, 0, stream>>>(bsum, btop, NBLK);
        scan_add<<<NBLK, 256, 0, stream>>>(off, btop, cursor, cnt, NN);
        fill_kernel<<<(EE + 255) / 256, 256, 0, stream>>>(
            srcp, dstp, SW + (size_t)k * NC * EE, cursor, csr_src, swp, EE);

        cvt_h<<<(NN * 64 + 255) / 256, 256, 0, stream>>>(Hk, (unsigned int*)Hbf, NN * 64);

        // h8 = fp8(relu(Hbf @ Wp_all + bp))   [NN,768]
        mgemm<1, true><<<6 * MB, 256, 0, stream>>>(
            Hbf, 128, (const unsigned short*)nullptr, 0, 128,
            Wp_t, 128, bp, h8, 768, NN, 128, 6);

        gather6<<<NN / 2, 256, 0, stream>>>(h8, swp, csr_src, off, agg);

        // proj = relu([Hbf|agg] @ Wfull + bcomb)   [NN,384]
        mgemm<0, true><<<3 * MB, 256, 0, stream>>>(
            Hbf, 128, agg, 768, 128,
            Wfull_t, 896, bcomb, proj, 384, NN, 896, 3);

        // xs_k = [Hbf|proj] @ Wpl + bpl   [NN,128]
        mgemm<0, false><<<1 * MB, 256, 0, stream>>>(
            Hbf, 128, proj, 384, 128,
            Wpl_t, 512, bpl, xs + (size_t)k * NN * 128, 128, NN, 512, 1);
    }

    // ---- fused LSTM ----
    lstm_fused<<<(NN + 31) / 32, 512, 0, stream>>>(xs, WihWhh_t, bias_lstm,
                                                   (float*)d_out);
}

// Round 8
// 738.289 us; speedup vs baseline: 5.5375x; 1.0668x over previous
//
#include <hip/hip_runtime.h>
#include <math.h>

constexpr int NN  = 30000;
constexpr int DIM = 128;
constexpr int KH  = 3;
constexpr int NC  = 6;
constexpr int EE  = 480000;
constexpr int NBLK3 = (3 * NN + 255) / 256;   // 352 scan blocks (batched)

typedef __attribute__((ext_vector_type(8))) short short8;
typedef __attribute__((ext_vector_type(4))) float f32x4;
typedef __attribute__((ext_vector_type(2))) float f32x2;

__device__ __forceinline__ unsigned short f2bf(float f) {
    union { float f; unsigned int i; } c; c.f = f;
    unsigned int u = c.i;
    return (unsigned short)((u + 0x7fffu + ((u >> 16) & 1u)) >> 16);
}
__device__ __forceinline__ float bf2f(unsigned int u) {
    union { unsigned int i; float f; } c; c.i = u << 16; return c.f;
}
__device__ __forceinline__ unsigned int packbf(float x, float y) {
    return (unsigned int)f2bf(x) | ((unsigned int)f2bf(y) << 16);
}
__device__ __forceinline__ float fsig(float x) {
    return __builtin_amdgcn_rcpf(1.f + __expf(-x));
}
__device__ __forceinline__ float ftanh(float x) {
    return 2.f * fsig(2.f * x) - 1.f;
}

// ---------------------------------------------------------------------------
// bf16 MFMA GEMM (unchanged): C[M,N] = act(A@B + bias), Bt[N,K] transposed.
// ---------------------------------------------------------------------------
template<int OUT, bool RELU>
__global__ __launch_bounds__(256) void mgemm(
    const unsigned short* __restrict__ A1, int lda1,
    const unsigned short* __restrict__ A2, int lda2, int ksplit,
    const unsigned short* __restrict__ Bt, int ldb,
    const float* __restrict__ bias,
    void* __restrict__ Cv, int ldc,
    int M, int K, int nx)
{
    __shared__ __align__(16) unsigned char smem[2 * 128 * 80];
    unsigned char* As = smem;
    unsigned char* Bs = smem + 128 * 80;

    const int nwg  = gridDim.x;
    const int orig = blockIdx.x;
    const int q = nwg >> 3, r = nwg & 7;
    const int xcd = orig & 7, idx = orig >> 3;
    const int lin = (xcd < r ? xcd * (q + 1) : r * (q + 1) + (xcd - r) * q) + idx;
    const int bx = lin % nx, by = lin / nx;

    const int tid  = threadIdx.x;
    const int lane = tid & 63;
    const int w    = tid >> 6;
    const int wm   = w >> 1, wn = w & 1;
    const int lm   = lane & 15, lg = lane >> 4;
    const int bm   = by * 128;
    const int bn   = bx * 128;

    const int srow  = tid >> 1;
    const int shalf = tid & 1;

    f32x4 acc[4][4] = {};

    int arow = bm + srow; if (arow > M - 1) arow = M - 1;
    const int brow = bn + srow;

    for (int k0 = 0; k0 < K; k0 += 32) {
        const unsigned short* Ap; int la; int kk;
        if (k0 < ksplit) { Ap = A1; la = lda1; kk = k0; }
        else             { Ap = A2; la = lda2; kk = k0 - ksplit; }
        const float4* ga = (const float4*)(Ap + (size_t)arow * la + kk + shalf * 16);
        float4 a0 = ga[0], a1 = ga[1];
        const float4* gb = (const float4*)(Bt + (size_t)brow * ldb + k0 + shalf * 16);
        float4 b0 = gb[0], b1 = gb[1];

        __syncthreads();
        *(float4*)(As + srow * 80 + shalf * 32)      = a0;
        *(float4*)(As + srow * 80 + shalf * 32 + 16) = a1;
        *(float4*)(Bs + srow * 80 + shalf * 32)      = b0;
        *(float4*)(Bs + srow * 80 + shalf * 32 + 16) = b1;
        __syncthreads();

        short8 av[4], bv[4];
        #pragma unroll
        for (int f = 0; f < 4; ++f) {
            av[f] = *(const short8*)(As + (wm * 64 + f * 16 + lm) * 80 + lg * 16);
            bv[f] = *(const short8*)(Bs + (wn * 64 + f * 16 + lm) * 80 + lg * 16);
        }
        #pragma unroll
        for (int i = 0; i < 4; ++i)
            #pragma unroll
            for (int j = 0; j < 4; ++j)
                acc[i][j] = __builtin_amdgcn_mfma_f32_16x16x32_bf16(
                    av[i], bv[j], acc[i][j], 0, 0, 0);
    }

    #pragma unroll
    for (int i = 0; i < 4; ++i) {
        int row0 = bm + wm * 64 + i * 16 + lg * 4;
        #pragma unroll
        for (int j = 0; j < 4; ++j) {
            int col = bn + wn * 64 + j * 16 + lm;
            float bb = bias[col];
            #pragma unroll
            for (int r = 0; r < 4; ++r) {
                int row = row0 + r;
                if (row < M) {
                    float v = acc[i][j][r] + bb;
                    if (RELU) v = fmaxf(v, 0.f);
                    if (OUT == 0) {
                        ((unsigned short*)Cv)[(size_t)row * ldc + col] = f2bf(v);
                    } else {
                        unsigned int pk = __builtin_amdgcn_cvt_pk_fp8_f32(v, v, 0, false);
                        ((unsigned char*)Cv)[(size_t)row * ldc + col] = (unsigned char)pk;
                    }
                }
            }
        }
    }
}

// ---------------------------------------------------------------------------
// Batched CSR build over the 3 graphs (off[g*NN+n]; graph g edges occupy
// csr positions [g*EE, (g+1)*EE) since each graph has exactly EE edges).
// ---------------------------------------------------------------------------
__global__ void hist3(const int* __restrict__ EL, int* __restrict__ cnt)
{
    int i = blockIdx.x * 256 + threadIdx.x;
    if (i >= 3 * EE) return;
    int g = i / EE;
    int e = i - g * EE;
    int dst = EL[(size_t)g * 2 * EE + EE + e];
    atomicAdd(&cnt[g * NN + dst], 1);
}

__global__ __launch_bounds__(256) void scan_part(const int* __restrict__ cnt,
                                                 int* __restrict__ off,
                                                 int* __restrict__ bsum, int n)
{
    int lane = threadIdx.x & 63, wid = threadIdx.x >> 6;
    int i = blockIdx.x * 256 + threadIdx.x;
    int v = (i < n) ? cnt[i] : 0;
    int x = v;
    #pragma unroll
    for (int ofs = 1; ofs < 64; ofs <<= 1) {
        int t = __shfl_up(x, ofs, 64);
        if (lane >= ofs) x += t;
    }
    __shared__ int ws[4];
    if (lane == 63) ws[wid] = x;
    __syncthreads();
    int wo = 0;
    for (int j = 0; j < wid; ++j) wo += ws[j];
    if (i < n) off[i] = wo + x - v;
    if (threadIdx.x == 255) bsum[blockIdx.x] = wo + x;
}

__global__ __launch_bounds__(512) void scan_tops(const int* __restrict__ bsum,
                                                 int* __restrict__ btop, int nb)
{
    __shared__ int buf[512];
    int v = (threadIdx.x < nb) ? bsum[threadIdx.x] : 0;
    buf[threadIdx.x] = v;
    __syncthreads();
    #pragma unroll
    for (int ofs = 1; ofs < 512; ofs <<= 1) {
        int t = (threadIdx.x >= ofs) ? buf[threadIdx.x - ofs] : 0;
        __syncthreads();
        buf[threadIdx.x] += t;
        __syncthreads();
    }
    if (threadIdx.x < nb) btop[threadIdx.x] = buf[threadIdx.x] - v;
}

__global__ __launch_bounds__(256) void scan_add(int* __restrict__ off,
                                                const int* __restrict__ btop,
                                                int* __restrict__ cursor,
                                                int n, int etot)
{
    int i = blockIdx.x * 256 + threadIdx.x;
    if (i < n) {
        int o = off[i] + btop[blockIdx.x];
        off[i] = o;
        cursor[i] = o;
    }
    if (blockIdx.x == 0 && threadIdx.x == 0) off[n] = etot;
}

__global__ void fill3(const int* __restrict__ EL, const float* __restrict__ SW,
                      int* __restrict__ cursor, int* __restrict__ csr_src,
                      uint2* __restrict__ swp)
{
    int i = blockIdx.x * 256 + threadIdx.x;
    if (i >= 3 * EE) return;
    int g = i / EE;
    int e = i - g * EE;
    const int* base = EL + (size_t)g * 2 * EE;
    int src = base[e], dst = base[EE + e];
    int pos = atomicAdd(&cursor[g * NN + dst], 1);
    csr_src[pos] = src;
    const float* sw = SW + (size_t)g * NC * EE;
    uint2 lo, hi;
    lo.x = packbf(sw[e],                   sw[(size_t)EE + e]);
    lo.y = packbf(sw[2 * (size_t)EE + e],  0.f);
    hi.x = packbf(sw[3 * (size_t)EE + e],  sw[4 * (size_t)EE + e]);
    hi.y = packbf(sw[5 * (size_t)EE + e],  0.f);
    swp[(size_t)pos * 2]     = lo;
    swp[(size_t)pos * 2 + 1] = hi;
}

// ---------------------------------------------------------------------------
// Fused 6-conv weighted segment-mean gather, unroll-4 (unchanged core).
// off is per-graph (off + k*NN); csr/swp indices are global.
// ---------------------------------------------------------------------------
__global__ __launch_bounds__(256) void gather6(
    const unsigned char* __restrict__ h8,
    const uint2* __restrict__ swp,
    const int* __restrict__ csr_src,
    const int* __restrict__ off,
    unsigned short* __restrict__ agg)
{
    int wid  = threadIdx.x >> 6;
    int lane = threadIdx.x & 63;
    int node = blockIdx.x * 2 + (wid >> 1);
    int half = wid & 1;
    if (node >= NN) return;
    int s0 = off[node], s1 = off[node + 1];
    float a0 = 0.f, a1 = 0.f, b0 = 0.f, b1 = 0.f, c0 = 0.f, c1 = 0.f;
    const size_t hofs = (size_t)half * 384 + (size_t)lane * 2;

    int e = s0;
    for (; e + 3 < s1; e += 4) {
        int sA = csr_src[e],     sB = csr_src[e + 1];
        int sC = csr_src[e + 2], sD = csr_src[e + 3];
        uint2 wA = swp[(size_t)(e    ) * 2 + half];
        uint2 wB = swp[(size_t)(e + 1) * 2 + half];
        uint2 wC = swp[(size_t)(e + 2) * 2 + half];
        uint2 wD = swp[(size_t)(e + 3) * 2 + half];
        const unsigned short* rA = (const unsigned short*)(h8 + (size_t)sA * 768 + hofs);
        const unsigned short* rB = (const unsigned short*)(h8 + (size_t)sB * 768 + hofs);
        const unsigned short* rC = (const unsigned short*)(h8 + (size_t)sC * 768 + hofs);
        const unsigned short* rD = (const unsigned short*)(h8 + (size_t)sD * 768 + hofs);
        unsigned int pA0 = rA[0], pA1 = rA[64], pA2 = rA[128];
        unsigned int pB0 = rB[0], pB1 = rB[64], pB2 = rB[128];
        unsigned int pC0 = rC[0], pC1 = rC[64], pC2 = rC[128];
        unsigned int pD0 = rD[0], pD1 = rD[64], pD2 = rD[128];

        {
            float w0 = bf2f(wA.x & 0xffffu), w1 = bf2f(wA.x >> 16), w2 = bf2f(wA.y & 0xffffu);
            f32x2 h0 = __builtin_amdgcn_cvt_pk_f32_fp8(pA0, false);
            f32x2 h1 = __builtin_amdgcn_cvt_pk_f32_fp8(pA1, false);
            f32x2 h2 = __builtin_amdgcn_cvt_pk_f32_fp8(pA2, false);
            a0 += w0 * h0.x; a1 += w0 * h0.y;
            b0 += w1 * h1.x; b1 += w1 * h1.y;
            c0 += w2 * h2.x; c1 += w2 * h2.y;
        }
        {
            float w0 = bf2f(wB.x & 0xffffu), w1 = bf2f(wB.x >> 16), w2 = bf2f(wB.y & 0xffffu);
            f32x2 h0 = __builtin_amdgcn_cvt_pk_f32_fp8(pB0, false);
            f32x2 h1 = __builtin_amdgcn_cvt_pk_f32_fp8(pB1, false);
            f32x2 h2 = __builtin_amdgcn_cvt_pk_f32_fp8(pB2, false);
            a0 += w0 * h0.x; a1 += w0 * h0.y;
            b0 += w1 * h1.x; b1 += w1 * h1.y;
            c0 += w2 * h2.x; c1 += w2 * h2.y;
        }
        {
            float w0 = bf2f(wC.x & 0xffffu), w1 = bf2f(wC.x >> 16), w2 = bf2f(wC.y & 0xffffu);
            f32x2 h0 = __builtin_amdgcn_cvt_pk_f32_fp8(pC0, false);
            f32x2 h1 = __builtin_amdgcn_cvt_pk_f32_fp8(pC1, false);
            f32x2 h2 = __builtin_amdgcn_cvt_pk_f32_fp8(pC2, false);
            a0 += w0 * h0.x; a1 += w0 * h0.y;
            b0 += w1 * h1.x; b1 += w1 * h1.y;
            c0 += w2 * h2.x; c1 += w2 * h2.y;
        }
        {
            float w0 = bf2f(wD.x & 0xffffu), w1 = bf2f(wD.x >> 16), w2 = bf2f(wD.y & 0xffffu);
            f32x2 h0 = __builtin_amdgcn_cvt_pk_f32_fp8(pD0, false);
            f32x2 h1 = __builtin_amdgcn_cvt_pk_f32_fp8(pD1, false);
            f32x2 h2 = __builtin_amdgcn_cvt_pk_f32_fp8(pD2, false);
            a0 += w0 * h0.x; a1 += w0 * h0.y;
            b0 += w1 * h1.x; b1 += w1 * h1.y;
            c0 += w2 * h2.x; c1 += w2 * h2.y;
        }
    }
    for (; e < s1; ++e) {
        int src = csr_src[e];
        uint2 wv = swp[(size_t)e * 2 + half];
        float w0 = bf2f(wv.x & 0xffffu);
        float w1 = bf2f(wv.x >> 16);
        float w2 = bf2f(wv.y & 0xffffu);
        const unsigned short* hrow = (const unsigned short*)(h8 + (size_t)src * 768 + hofs);
        unsigned int p0 = hrow[0];
        unsigned int p1 = hrow[64];
        unsigned int p2 = hrow[128];
        f32x2 h0 = __builtin_amdgcn_cvt_pk_f32_fp8(p0, false);
        f32x2 h1 = __builtin_amdgcn_cvt_pk_f32_fp8(p1, false);
        f32x2 h2 = __builtin_amdgcn_cvt_pk_f32_fp8(p2, false);
        a0 += w0 * h0.x; a1 += w0 * h0.y;
        b0 += w1 * h1.x; b1 += w1 * h1.y;
        c0 += w2 * h2.x; c1 += w2 * h2.y;
    }
    float inv = 1.f / fmaxf((float)(s1 - s0), 1.f);
    unsigned int* orow = (unsigned int*)(agg + (size_t)node * 768) + 192 * half + lane;
    orow[0]   = packbf(a0 * inv, a1 * inv);
    orow[64]  = packbf(b0 * inv, b1 * inv);
    orow[128] = packbf(c0 * inv, c1 * inv);
}

// ---------------------------------------------------------------------------
__global__ void cvt_h(const float* __restrict__ Hk, unsigned int* __restrict__ out,
                      int total)
{
    int idx = blockIdx.x * 256 + threadIdx.x;
    if (idx >= total) return;
    float2 v = ((const float2*)Hk)[idx];
    out[idx] = packbf(v.x, v.y);
}

// ---------------------------------------------------------------------------
// Fused 3-step LSTM (unchanged from r7: weights hoisted to registers).
// ---------------------------------------------------------------------------
#define SWA32(r, b) ((r) * 512 + ((b) ^ (((r) & 7) << 4)))

__global__ __launch_bounds__(512) void lstm_fused(
    const unsigned short* __restrict__ xs,   // [3][NN][128]
    const unsigned short* __restrict__ Wt,   // [512][256] permuted rows
    const float* __restrict__ bsum,          // [512] permuted
    float* __restrict__ outp)                // [NN][128]
{
    __shared__ __align__(16) unsigned char AL[32 * 512];

    const int tid  = threadIdx.x;
    const int lane = tid & 63;
    const int w    = tid >> 6;              // 0..7
    const int lm   = lane & 15, lg = lane >> 4;
    const int node0 = blockIdx.x * 32;

    float bias[4];
    #pragma unroll
    for (int g = 0; g < 4; ++g)
        bias[g] = bsum[w * 64 + g * 16 + lm];

    short8 bw[8][4];
    #pragma unroll
    for (int ks = 0; ks < 8; ++ks)
        #pragma unroll
        for (int g = 0; g < 4; ++g)
            bw[ks][g] = *(const short8*)(Wt +
                (size_t)(w * 64 + g * 16 + lm) * 256 + ks * 32 + lg * 8);

    float cst[2][4] = {};

    float4 z4 = make_float4(0.f, 0.f, 0.f, 0.f);
    {
        int r = tid >> 4, gi = tid & 15;
        *(float4*)(AL + SWA32(r, 256 + gi * 16)) = z4;
    }

    for (int t = 0; t < KH; ++t) {
        const unsigned short* xsrc = xs + (size_t)t * NN * 128;
        {
            int r = tid >> 4, gi = tid & 15;
            int gr = node0 + r; if (gr >= NN) gr = NN - 1;
            float4 v = *(const float4*)(xsrc + (size_t)gr * 128 + gi * 8);
            *(float4*)(AL + SWA32(r, gi * 16)) = v;
        }
        __syncthreads();

        f32x4 acc[2][4] = {};
        #pragma unroll
        for (int ks = 0; ks < 8; ++ks) {
            short8 av[2];
            #pragma unroll
            for (int i = 0; i < 2; ++i)
                av[i] = *(const short8*)(AL + SWA32(i * 16 + lm, ks * 64 + lg * 16));
            #pragma unroll
            for (int g = 0; g < 4; ++g)
                #pragma unroll
                for (int i = 0; i < 2; ++i)
                    acc[i][g] = __builtin_amdgcn_mfma_f32_16x16x32_bf16(
                        av[i], bw[ks][g], acc[i][g], 0, 0, 0);
        }
        __syncthreads();

        #pragma unroll
        for (int i = 0; i < 2; ++i)
            #pragma unroll
            for (int r = 0; r < 4; ++r) {
                float giv = acc[i][0][r] + bias[0];
                float gfv = acc[i][1][r] + bias[1];
                float ggv = acc[i][2][r] + bias[2];
                float gov = acc[i][3][r] + bias[3];
                float si = fsig(giv);
                float sf = fsig(gfv);
                float so = fsig(gov);
                float cv = sf * cst[i][r] + si * ftanh(ggv);
                cst[i][r] = cv;
                float hv = so * ftanh(cv);
                int row = i * 16 + lg * 4 + r;
                int d   = w * 16 + lm;
                if (t < KH - 1) {
                    *(unsigned short*)(AL + SWA32(row, 256 + 2 * d)) = f2bf(hv);
                } else if (node0 + row < NN) {
                    outp[(size_t)(node0 + row) * 128 + d] = fmaxf(hv, 0.f);
                }
            }
    }
}

// ---------------------------------------------------------------------------
// Weight precompute: tiled fp32 GEMM fold (replaces scalar wt_full).
// Wfull[m][n], m in [0,896), n in [0,384):
//   m<128:  Wcomb[m][n] + sum_i Wroot_i @ Wcomb_blk(i)
//   else:   (Wrel_i @ Wcomb_blk(i))[m&127][n],  i = (m>>7)-1
// Written transposed bf16: Wfull_t[n*896+m]. 64x64 tile, 4x4/thread.
// ---------------------------------------------------------------------------
__global__ __launch_bounds__(256) void wt_fold(
    const float* __restrict__ Wcomb,     // [896][384] (only rows 0..895 used)
    const float* __restrict__ Wroot,     // [6][128][128]
    const float* __restrict__ Wrel,      // [6][128][128]
    unsigned short* __restrict__ Wfull_t)// [384][896]
{
    __shared__ __align__(16) float As[16][68];
    __shared__ __align__(16) float Bs[16][68];
    const int tid = threadIdx.x;
    const int tx = tid & 15, ty = tid >> 4;
    const int bm = blockIdx.y * 64;   // 14 tiles
    const int bn = blockIdx.x * 64;   // 6 tiles
    const bool root = (bm < 128);
    const int i0 = root ? 0 : (bm >> 7) - 1;
    const int i1 = root ? NC : i0 + 1;
    const int mloc = bm & 127;
    const int a_m = tid >> 2, a_k = (tid & 3) * 4;
    const int b_k = tid >> 4, b_n = (tid & 15) * 4;

    float acc[4][4] = {};

    for (int i = i0; i < i1; ++i) {
        const float* A = (root ? Wroot : Wrel) + (size_t)i * 128 * 128;
        const float* B = Wcomb + (size_t)(i + 1) * 128 * 384;
        for (int k0 = 0; k0 < 128; k0 += 16) {
            float4 va = *(const float4*)(A + (size_t)(mloc + a_m) * 128 + k0 + a_k);
            float4 vb = *(const float4*)(B + (size_t)(k0 + b_k) * 384 + bn + b_n);
            __syncthreads();
            As[a_k + 0][a_m] = va.x; As[a_k + 1][a_m] = va.y;
            As[a_k + 2][a_m] = va.z; As[a_k + 3][a_m] = va.w;
            *(float4*)&Bs[b_k][b_n] = vb;
            __syncthreads();
            #pragma unroll
            for (int kk = 0; kk < 16; ++kk) {
                float4 av = *(const float4*)&As[kk][ty * 4];
                float4 bv = *(const float4*)&Bs[kk][tx * 4];
                float a[4] = {av.x, av.y, av.z, av.w};
                float b[4] = {bv.x, bv.y, bv.z, bv.w};
                #pragma unroll
                for (int ii = 0; ii < 4; ++ii)
                    #pragma unroll
                    for (int j = 0; j < 4; ++j)
                        acc[ii][j] += a[ii] * b[j];
            }
        }
    }

    #pragma unroll
    for (int ii = 0; ii < 4; ++ii) {
        int m = bm + ty * 4 + ii;
        #pragma unroll
        for (int j = 0; j < 4; ++j) {
            int n = bn + tx * 4 + j;
            float v = acc[ii][j];
            if (root) v += Wcomb[(size_t)m * 384 + n];
            Wfull_t[(size_t)n * 896 + m] = f2bf(v);
        }
    }
}

// ---------------------------------------------------------------------------
// Transpose-convert: dst[c][r] (bf16) = src[r][c] (fp32); batch via blockIdx.z
// (both strides R*C). 32x32 tile, 256 threads.
// ---------------------------------------------------------------------------
__global__ __launch_bounds__(256) void tr_cvt(
    const float* __restrict__ src, unsigned short* __restrict__ dst,
    int R, int C)
{
    __shared__ float s[32][33];
    const float* sb = src + (size_t)blockIdx.z * R * C;
    unsigned short* db = dst + (size_t)blockIdx.z * R * C;
    int r0 = blockIdx.y * 32, c0 = blockIdx.x * 32;
    int tx = threadIdx.x & 31, ty = threadIdx.x >> 5;   // 32x8
    #pragma unroll
    for (int q = 0; q < 4; ++q)
        s[ty + q * 8][tx] = sb[(size_t)(r0 + ty + q * 8) * C + c0 + tx];
    __syncthreads();
    #pragma unroll
    for (int q = 0; q < 4; ++q)
        db[(size_t)(c0 + ty + q * 8) * R + r0 + tx] = f2bf(s[tx][ty + q * 8]);
}

// Gate-interleaved LSTM weights (coalesced reads; unchanged math).
__global__ void wt_lstm(const float* __restrict__ Wih, const float* __restrict__ Whh,
                        const float* __restrict__ bih, const float* __restrict__ bhh,
                        unsigned short* __restrict__ Wt, float* __restrict__ bsum)
{
    int idx = blockIdx.x * 256 + threadIdx.x;
    if (idx < 512) {
        int w = idx >> 6, rem = idx & 63, g = rem >> 4, d16 = rem & 15;
        int n = g * 128 + w * 16 + d16;
        bsum[idx] = bih[n] + bhh[n];
    }
    if (idx >= 512 * 256) return;
    int k = idx & 255, np = idx >> 8;
    int w = np >> 6, rem = np & 63, g = rem >> 4, d16 = rem & 15;
    int n = g * 128 + w * 16 + d16;
    Wt[idx] = f2bf(k < 128 ? Wih[(size_t)n * DIM + k]
                           : Whh[(size_t)n * DIM + (k - 128)]);
}

// ---------------------------------------------------------------------------
extern "C" void kernel_launch(void* const* d_in, const int* in_sizes, int n_in,
                              void* d_out, int out_size, void* d_ws, size_t ws_size,
                              hipStream_t stream)
{
    const float* H     = (const float*)d_in[0];
    const int*   EL    = (const int*)  d_in[1];
    const float* SW    = (const float*)d_in[2];
    const float* Wp    = (const float*)d_in[3];
    const float* bp    = (const float*)d_in[4];
    const float* Wrel  = (const float*)d_in[5];
    const float* Wroot = (const float*)d_in[6];
    const float* Wcomb = (const float*)d_in[7];
    const float* bcomb = (const float*)d_in[8];
    const float* Wpl   = (const float*)d_in[9];
    const float* bpl   = (const float*)d_in[10];
    const float* Wih   = (const float*)d_in[11];
    const float* Whh   = (const float*)d_in[12];
    const float* bih   = (const float*)d_in[13];
    const float* bhh   = (const float*)d_in[14];

    char* wp = (char*)d_ws;
    auto alloc = [&](size_t b) {
        char* p = wp; wp += (b + 255) & ~(size_t)255; return p;
    };
    unsigned short* Hbf  = (unsigned short*)alloc((size_t)3 * NN * 128 * 2);
    unsigned char*  h8   = (unsigned char*) alloc((size_t)NN * 768);
    unsigned short* agg  = (unsigned short*)alloc((size_t)NN * 768 * 2);
    unsigned short* proj = (unsigned short*)alloc((size_t)NN * 384 * 2);
    unsigned short* xs   = (unsigned short*)alloc((size_t)KH * NN * 128 * 2);
    int* cnt     = (int*)alloc((size_t)3 * NN * 4);
    int* off     = (int*)alloc((size_t)(3 * NN + 1) * 4);
    int* cursor  = (int*)alloc((size_t)3 * NN * 4);
    int* bsum    = (int*)alloc((size_t)NBLK3 * 4);
    int* btop    = (int*)alloc((size_t)NBLK3 * 4);
    int* csr_src = (int*)alloc((size_t)3 * EE * 4);
    uint2* swp   = (uint2*)alloc((size_t)3 * EE * 16);
    unsigned short* Wp_t     = (unsigned short*)alloc((size_t)768 * 128 * 2);
    unsigned short* Wfull_t  = (unsigned short*)alloc((size_t)384 * 896 * 2);
    unsigned short* Wpl_t    = (unsigned short*)alloc((size_t)128 * 512 * 2);
    unsigned short* WihWhh_t = (unsigned short*)alloc((size_t)512 * 256 * 2);
    float* bias_lstm         = (float*)alloc(512 * 4);

    // ---- weight precompute ----
    tr_cvt<<<dim3(4, 4, 6), 256, 0, stream>>>(Wp, Wp_t, 128, 128);
    wt_fold<<<dim3(6, 14), 256, 0, stream>>>(Wcomb, Wroot, Wrel, Wfull_t);
    tr_cvt<<<dim3(4, 16, 1), 256, 0, stream>>>(Wpl, Wpl_t, 512, 128);
    wt_lstm<<<(512 * 256 + 255) / 256, 256, 0, stream>>>(Wih, Whh, bih, bhh,
                                                         WihWhh_t, bias_lstm);

    // ---- batched CSR build over all 3 graphs ----
    hipMemsetAsync(cnt, 0, (size_t)3 * NN * 4, stream);
    hist3<<<(3 * EE + 255) / 256, 256, 0, stream>>>(EL, cnt);
    scan_part<<<NBLK3, 256, 0, stream>>>(cnt, off, bsum, 3 * NN);
    scan_tops<<<1, 512, 0, stream>>>(bsum, btop, NBLK3);
    scan_add<<<NBLK3, 256, 0, stream>>>(off, btop, cursor, 3 * NN, 3 * EE);
    fill3<<<(3 * EE + 255) / 256, 256, 0, stream>>>(EL, SW, cursor, csr_src, swp);

    // ---- batched fp32->bf16 convert of all H ----
    cvt_h<<<(3 * NN * 64 + 255) / 256, 256, 0, stream>>>(H, (unsigned int*)Hbf,
                                                         3 * NN * 64);

    const int MB = (NN + 127) / 128;   // 235

    for (int k = 0; k < KH; ++k) {
        const unsigned short* Hbk = Hbf + (size_t)k * NN * 128;

        // h8 = fp8(relu(Hbk @ Wp_all + bp))   [NN,768]
        mgemm<1, true><<<6 * MB, 256, 0, stream>>>(
            Hbk, 128, (const unsigned short*)nullptr, 0, 128,
            Wp_t, 128, bp, h8, 768, NN, 128, 6);

        gather6<<<NN / 2, 256, 0, stream>>>(h8, swp, csr_src, off + k * NN, agg);

        // proj = relu([Hbk|agg] @ Wfull + bcomb)   [NN,384]
        mgemm<0, true><<<3 * MB, 256, 0, stream>>>(
            Hbk, 128, agg, 768, 128,
            Wfull_t, 896, bcomb, proj, 384, NN, 896, 3);

        // xs_k = [Hbk|proj] @ Wpl + bpl   [NN,128]
        mgemm<0, false><<<1 * MB, 256, 0, stream>>>(
            Hbk, 128, proj, 384, 128,
            Wpl_t, 512, bpl, xs + (size_t)k * NN * 128, 128, NN, 512, 1);
    }

    // ---- fused LSTM ----
    lstm_fused<<<(NN + 31) / 32, 512, 0, stream>>>(xs, WihWhh_t, bias_lstm,
                                                   (float*)d_out);
}